// Round 1
// baseline (1787.601 us; speedup 1.0000x reference)
//
#include <hip/hip_runtime.h>

#define H 12
#define T 2048
#define D 768
#define NBT 4096            // B*T
#define SCALE 0.125f
#define DECAY_F 0.99f

// ---------------- generic fp32 GEMM: C[M,N] = A[M,K] @ W[N,K]^T (+bias) ----
// grid: ((N+63)/64, M/64), 256 threads, 4x4 micro-tile per thread
__global__ __launch_bounds__(256) void gemm64(
    const float* __restrict__ A, const float* __restrict__ W,
    const float* __restrict__ bias, float* __restrict__ C,
    int N, int K, int ldc)
{
  __shared__ float As[16][68];
  __shared__ float Ws[16][68];
  const int bm = blockIdx.y * 64;
  const int bn = blockIdx.x * 64;
  const int tid = threadIdx.x;
  const int tm = tid >> 4, tn = tid & 15;
  const int lr = tid >> 2;
  const int lk = (tid & 3) * 4;
  const float* Ap = A + (size_t)(bm + lr) * K + lk;
  const bool wv = (bn + lr) < N;
  const float* Wp = W + (size_t)(wv ? (bn + lr) : 0) * K + lk;
  float acc[4][4] = {};
  for (int k0 = 0; k0 < K; k0 += 16) {
    float4 a4 = *(const float4*)(Ap + k0);
    float4 w4 = wv ? *(const float4*)(Wp + k0) : make_float4(0.f, 0.f, 0.f, 0.f);
    __syncthreads();
    As[lk + 0][lr] = a4.x; As[lk + 1][lr] = a4.y; As[lk + 2][lr] = a4.z; As[lk + 3][lr] = a4.w;
    Ws[lk + 0][lr] = w4.x; Ws[lk + 1][lr] = w4.y; Ws[lk + 2][lr] = w4.z; Ws[lk + 3][lr] = w4.w;
    __syncthreads();
#pragma unroll
    for (int kk = 0; kk < 16; kk++) {
      const float4 a = *(const float4*)&As[kk][tm * 4];
      const float4 b = *(const float4*)&Ws[kk][tn * 4];
      acc[0][0] += a.x * b.x; acc[0][1] += a.x * b.y; acc[0][2] += a.x * b.z; acc[0][3] += a.x * b.w;
      acc[1][0] += a.y * b.x; acc[1][1] += a.y * b.y; acc[1][2] += a.y * b.z; acc[1][3] += a.y * b.w;
      acc[2][0] += a.z * b.x; acc[2][1] += a.z * b.y; acc[2][2] += a.z * b.z; acc[2][3] += a.z * b.w;
      acc[3][0] += a.w * b.x; acc[3][1] += a.w * b.y; acc[3][2] += a.w * b.z; acc[3][3] += a.w * b.w;
    }
  }
#pragma unroll
  for (int i = 0; i < 4; i++) {
    const int row = bm + tm * 4 + i;
#pragma unroll
    for (int j = 0; j < 4; j++) {
      const int col = bn + tn * 4 + j;
      if (col < N)
        C[(size_t)row * ldc + col] = acc[i][j] + (bias ? bias[col] : 0.f);
    }
  }
}

// ---------------- causal attention, streaming softmax ----------------
// grid: (B*H, T/64), 256 threads. Each thread: 1 q-row (4 threads/row), 16 s per tile.
__global__ __launch_bounds__(256) void attn_kernel(
    const float* __restrict__ qkv, float* __restrict__ seq)
{
  const int b = blockIdx.x / H, h = blockIdx.x % H;
  const int t0 = blockIdx.y * 64;
  const int tid = threadIdx.x;
  const int r = tid >> 2;
  const int sc = tid & 3;
  const int t = t0 + r;
  __shared__ float Ks[64][68];
  __shared__ float Vs[64][68];

  float qreg[64];
  {
    const float* qp = qkv + (size_t)(b * T + t) * 2304 + h * 64;
#pragma unroll
    for (int i = 0; i < 16; i++) {
      float4 v4 = *(const float4*)(qp + i * 4);
      qreg[i * 4 + 0] = v4.x; qreg[i * 4 + 1] = v4.y;
      qreg[i * 4 + 2] = v4.z; qreg[i * 4 + 3] = v4.w;
    }
  }
  float acc[64];
#pragma unroll
  for (int d = 0; d < 64; d++) acc[d] = 0.f;
  float lsum = 0.f;

  const int lr = tid >> 2;
  const int c0 = (tid & 3) * 16;
  const float* kb = qkv + (size_t)(b * T) * 2304 + D + h * 64;
  const float* vb = qkv + (size_t)(b * T) * 2304 + 2 * D + h * 64;

  for (int s0 = 0; s0 <= t0; s0 += 64) {
    __syncthreads();
    {
      const float* kp = kb + (size_t)(s0 + lr) * 2304 + c0;
      const float* vp = vb + (size_t)(s0 + lr) * 2304 + c0;
#pragma unroll
      for (int j = 0; j < 4; j++) {
        *(float4*)&Ks[lr][c0 + 4 * j] = *(const float4*)(kp + 4 * j);
        *(float4*)&Vs[lr][c0 + 4 * j] = *(const float4*)(vp + 4 * j);
      }
    }
    __syncthreads();
    float p[16];
#pragma unroll
    for (int i = 0; i < 16; i++) {
      const int sv = (sc << 4) + i;
      float d0 = 0.f, d1 = 0.f, d2 = 0.f, d3 = 0.f;
#pragma unroll
      for (int d = 0; d < 64; d += 4) {
        const float4 k4 = *(const float4*)&Ks[sv][d];
        d0 += qreg[d] * k4.x; d1 += qreg[d + 1] * k4.y;
        d2 += qreg[d + 2] * k4.z; d3 += qreg[d + 3] * k4.w;
      }
      const int s = s0 + sv;
      const float logit = ((d0 + d1) + (d2 + d3)) * SCALE;
      p[i] = (s <= t) ? __expf(logit) : 0.f;
      lsum += p[i];
    }
#pragma unroll
    for (int i = 0; i < 16; i++) {
      const int sv = (sc << 4) + i;
      const float pi = p[i];
#pragma unroll
      for (int d = 0; d < 64; d += 4) {
        const float4 v4 = *(const float4*)&Vs[sv][d];
        acc[d] += pi * v4.x; acc[d + 1] += pi * v4.y;
        acc[d + 2] += pi * v4.z; acc[d + 3] += pi * v4.w;
      }
    }
  }
  lsum += __shfl_xor(lsum, 1);
  lsum += __shfl_xor(lsum, 2);
  const float inv = 1.f / lsum;
  float tmp[16];
#pragma unroll
  for (int d = 0; d < 64; d++) {
    float a = acc[d];
    a += __shfl_xor(a, 1);
    a += __shfl_xor(a, 2);
    if ((d >> 4) == sc) tmp[d & 15] = a * inv;
  }
  float* op = seq + (size_t)(b * T + t) * D + h * 64 + c0;
#pragma unroll
  for (int j = 0; j < 4; j++)
    *(float4*)(op + 4 * j) = make_float4(tmp[4 * j], tmp[4 * j + 1],
                                         tmp[4 * j + 2], tmp[4 * j + 3]);
}

// ---------------- Plucker memory: chunked decay scan ----------------
__device__ __forceinline__ void ext_norm6(const float4 a, const float4 b, float* L)
{
  L[0] = a.x * b.y - a.y * b.x;
  L[1] = a.x * b.z - a.z * b.x;
  L[2] = a.x * b.w - a.w * b.x;
  L[3] = a.y * b.z - a.z * b.y;
  L[4] = a.y * b.w - a.w * b.y;
  L[5] = a.z * b.w - a.w * b.z;
  float n2 = L[0]*L[0] + L[1]*L[1] + L[2]*L[2] + L[3]*L[3] + L[4]*L[4] + L[5]*L[5];
  float n = fmaxf(sqrtf(n2), 1e-12f);
  float inv = 1.f / n;
#pragma unroll
  for (int i = 0; i < 6; i++) L[i] *= inv;
}

// grid: (B*H), 256 threads; thread i owns t in [8i, 8i+8)
__global__ __launch_bounds__(256) void memscan(
    const float* __restrict__ xw1w, const float* __restrict__ xw2w,
    const float* __restrict__ xw1r, const float* __restrict__ xw2r,
    const float* __restrict__ memg, const float* __restrict__ mem_scale,
    float* __restrict__ gated)
{
  const int b = blockIdx.x / H, h = blockIdx.x % H;
  const int tid = threadIdx.x;
  __shared__ float S[256][22];
  const int base = tid * 8;
  const size_t rb = (size_t)b * T;

  float M[21];
#pragma unroll
  for (int c = 0; c < 21; c++) M[c] = 0.f;
  float sloc[8];

  for (int j = 0; j < 8; j++) {
    const int t = base + j;
    const float4 w2 = *(const float4*)(xw2w + (rb + t) * 48 + h * 4);
    float C[21];
#pragma unroll
    for (int c = 0; c < 21; c++) C[c] = 0.f;
    const int offs[4] = {1, 2, 4, 8};
#pragma unroll
    for (int oi = 0; oi < 4; oi++) {
      const int off = offs[oi];
      if (t >= off) {
        const float4 w1 = *(const float4*)(xw1w + (rb + t - off) * 48 + h * 4);
        float L[6];
        ext_norm6(w1, w2, L);
        const float Jv[6] = { L[5], -L[4], L[3], L[2], -L[1], L[0] };
        int c = 0;
#pragma unroll
        for (int p = 0; p < 6; p++)
#pragma unroll
          for (int q = p; q < 6; q++) { C[c] += Jv[p] * Jv[q]; c++; }
      }
    }
    float R[6];
    {
      const float4 r1 = *(const float4*)(xw1r + (rb + t) * 48 + h * 4);
      const float4 r2 = *(const float4*)(xw2r + (rb + t) * 48 + h * 4);
      ext_norm6(r1, r2, R);
    }
    float qd = 0.f;
    {
      int c = 0;
#pragma unroll
      for (int p = 0; p < 6; p++) {
        qd += M[c] * R[p] * R[p]; c++;
#pragma unroll
        for (int q = p + 1; q < 6; q++) { qd += 2.f * M[c] * R[p] * R[q]; c++; }
      }
    }
    sloc[j] = qd;
#pragma unroll
    for (int cc = 0; cc < 21; cc++) M[cc] = DECAY_F * (M[cc] + C[cc]);
  }

#pragma unroll
  for (int c = 0; c < 21; c++) S[tid][c] = M[c];
  __syncthreads();
  if (tid < 21) {                 // exclusive scan over 256 chunk carries
    float pv = 0.f;
    const float d8 = 0.92274469442792013f;  // 0.99^8
    for (int i = 0; i < 256; i++) {
      float a = S[i][tid];
      S[i][tid] = pv;
      pv = d8 * pv + a;
    }
  }
  __syncthreads();
  float P[21];
#pragma unroll
  for (int c = 0; c < 21; c++) P[c] = S[tid][c];

  const float msc = mem_scale[h];
  float dj = 1.f;
  for (int j = 0; j < 8; j++) {
    const int t = base + j;
    float R[6];
    {
      const float4 r1 = *(const float4*)(xw1r + (rb + t) * 48 + h * 4);
      const float4 r2 = *(const float4*)(xw2r + (rb + t) * 48 + h * 4);
      ext_norm6(r1, r2, R);
    }
    float qd = 0.f;
    {
      int c = 0;
#pragma unroll
      for (int p = 0; p < 6; p++) {
        qd += P[c] * R[p] * R[p]; c++;
#pragma unroll
        for (int q = p + 1; q < 6; q++) { qd += 2.f * P[c] * R[p] * R[q]; c++; }
      }
    }
    const float score = (sloc[j] + dj * qd) * 0.25f;
    const float g1 = 1.f / (1.f + __expf(-score * msc));
    const float graw = memg[(rb + t) * H + h];
    const float g2 = 1.f / (1.f + __expf(-graw));
    atomicAdd(&gated[rb + t], g1 * g2 * (1.f / 12.f));
    dj *= DECAY_F;
  }
}

// ---------------- z = seq + gated * memv ----------------
__global__ void fuse_z(const float* __restrict__ seq, const float* __restrict__ memv,
                       const float* __restrict__ gated, float* __restrict__ z)
{
  const int row = blockIdx.x;
  const int c4 = threadIdx.x;  // 192 threads * float4 = 768
  const float g = gated[row];
  const float4 s4 = *(const float4*)(seq + (size_t)row * D + c4 * 4);
  const float4 m4 = *(const float4*)(memv + (size_t)row * D + c4 * 4);
  float4 o;
  o.x = s4.x + g * m4.x; o.y = s4.y + g * m4.y;
  o.z = s4.z + g * m4.z; o.w = s4.w + g * m4.w;
  *(float4*)(z + (size_t)row * D + c4 * 4) = o;
}

extern "C" void kernel_launch(void* const* d_in, const int* in_sizes, int n_in,
                              void* d_out, int out_size, void* d_ws, size_t ws_size,
                              hipStream_t stream)
{
  const float* x      = (const float*)d_in[0];
  const float* qkv_w  = (const float*)d_in[1];
  const float* qkv_b  = (const float*)d_in[2];
  const float* w1w    = (const float*)d_in[3];
  const float* w2w    = (const float*)d_in[4];
  const float* w1r    = (const float*)d_in[5];
  const float* w2r    = (const float*)d_in[6];
  const float* memv_w = (const float*)d_in[7];
  const float* memv_b = (const float*)d_in[8];
  const float* memg_w = (const float*)d_in[9];
  const float* memg_b = (const float*)d_in[10];
  const float* mem_scale = (const float*)d_in[11];
  const float* out_w  = (const float*)d_in[12];
  const float* out_b  = (const float*)d_in[13];
  float* out = (float*)d_out;

  float* ws   = (float*)d_ws;
  float* qkvb = ws;                               // [NBT, 2304]
  float* seq  = qkvb + (size_t)NBT * 2304;        // [NBT, 768]
  float* memv = seq  + (size_t)NBT * D;           // [NBT, 768]
  float* zbuf = memv + (size_t)NBT * D;           // [NBT, 768]
  float* memg = zbuf + (size_t)NBT * D;           // [NBT, 12]
  float* xw1w = memg + (size_t)NBT * H;           // [NBT, 48]
  float* xw2w = xw1w + (size_t)NBT * 48;
  float* xw1r = xw2w + (size_t)NBT * 48;
  float* xw2r = xw1r + (size_t)NBT * 48;
  float* gated = xw2r + (size_t)NBT * 48;         // [NBT]

  dim3 blk(256);
  gemm64<<<dim3(36, 64), blk, 0, stream>>>(x, qkv_w, qkv_b, qkvb, 2304, D, 2304);
  gemm64<<<dim3(12, 64), blk, 0, stream>>>(x, memv_w, memv_b, memv, D, D, D);
  gemm64<<<dim3(1, 64),  blk, 0, stream>>>(x, memg_w, memg_b, memg, H, D, H);
  gemm64<<<dim3(1, 64),  blk, 0, stream>>>(x, w1w, nullptr, xw1w, 48, D, 48);
  gemm64<<<dim3(1, 64),  blk, 0, stream>>>(x, w2w, nullptr, xw2w, 48, D, 48);
  gemm64<<<dim3(1, 64),  blk, 0, stream>>>(x, w1r, nullptr, xw1r, 48, D, 48);
  gemm64<<<dim3(1, 64),  blk, 0, stream>>>(x, w2r, nullptr, xw2r, 48, D, 48);

  attn_kernel<<<dim3(2 * H, T / 64), blk, 0, stream>>>(qkvb, seq);

  hipMemsetAsync(gated, 0, NBT * sizeof(float), stream);
  memscan<<<dim3(2 * H), blk, 0, stream>>>(xw1w, xw2w, xw1r, xw2r, memg, mem_scale, gated);

  fuse_z<<<dim3(NBT), dim3(192), 0, stream>>>(seq, memv, gated, zbuf);
  gemm64<<<dim3(12, 64), blk, 0, stream>>>(zbuf, out_w, out_b, out, D, D, D);
}

// Round 2
// 665.974 us; speedup vs baseline: 2.6842x; 2.6842x over previous
//
#include <hip/hip_runtime.h>

#define H 12
#define T 2048
#define D 768
#define NBT 4096            // B*T
#define SCALE 0.125f
#define DECAY_F 0.99f

typedef __attribute__((ext_vector_type(8))) short bf16x8;
typedef __attribute__((ext_vector_type(16))) float f32x16;

static __device__ __forceinline__ ushort f2bf(float f) {
  union { float f; unsigned u; } v; v.f = f;
  unsigned r = (v.u + 0x7FFFu + ((v.u >> 16) & 1u)) >> 16;
  return (ushort)r;
}

// ---------------- generic fp32 GEMM: C[M,N] = A[M,K] @ W[N,K]^T (+bias) ----
__global__ __launch_bounds__(256) void gemm64(
    const float* __restrict__ A, const float* __restrict__ W,
    const float* __restrict__ bias, float* __restrict__ C,
    int N, int K, int ldc)
{
  __shared__ float As[16][68];
  __shared__ float Ws[16][68];
  const int bm = blockIdx.y * 64;
  const int bn = blockIdx.x * 64;
  const int tid = threadIdx.x;
  const int tm = tid >> 4, tn = tid & 15;
  const int lr = tid >> 2;
  const int lk = (tid & 3) * 4;
  const float* Ap = A + (size_t)(bm + lr) * K + lk;
  const bool wv = (bn + lr) < N;
  const float* Wp = W + (size_t)(wv ? (bn + lr) : 0) * K + lk;
  float acc[4][4] = {};
  for (int k0 = 0; k0 < K; k0 += 16) {
    float4 a4 = *(const float4*)(Ap + k0);
    float4 w4 = wv ? *(const float4*)(Wp + k0) : make_float4(0.f, 0.f, 0.f, 0.f);
    __syncthreads();
    As[lk + 0][lr] = a4.x; As[lk + 1][lr] = a4.y; As[lk + 2][lr] = a4.z; As[lk + 3][lr] = a4.w;
    Ws[lk + 0][lr] = w4.x; Ws[lk + 1][lr] = w4.y; Ws[lk + 2][lr] = w4.z; Ws[lk + 3][lr] = w4.w;
    __syncthreads();
#pragma unroll
    for (int kk = 0; kk < 16; kk++) {
      const float4 a = *(const float4*)&As[kk][tm * 4];
      const float4 b = *(const float4*)&Ws[kk][tn * 4];
      acc[0][0] += a.x * b.x; acc[0][1] += a.x * b.y; acc[0][2] += a.x * b.z; acc[0][3] += a.x * b.w;
      acc[1][0] += a.y * b.x; acc[1][1] += a.y * b.y; acc[1][2] += a.y * b.z; acc[1][3] += a.y * b.w;
      acc[2][0] += a.z * b.x; acc[2][1] += a.z * b.y; acc[2][2] += a.z * b.z; acc[2][3] += a.z * b.w;
      acc[3][0] += a.w * b.x; acc[3][1] += a.w * b.y; acc[3][2] += a.w * b.z; acc[3][3] += a.w * b.w;
    }
  }
#pragma unroll
  for (int i = 0; i < 4; i++) {
    const int row = bm + tm * 4 + i;
#pragma unroll
    for (int j = 0; j < 4; j++) {
      const int col = bn + tn * 4 + j;
      if (col < N)
        C[(size_t)row * ldc + col] = acc[i][j] + (bias ? bias[col] : 0.f);
    }
  }
}

// ---------------- QKV GEMM with bf16 epilogue into MFMA-friendly layouts ---
// Qb,Kb: [B*H][T][64] bf16;  Vtb: [B*H][64][T] bf16
__global__ __launch_bounds__(256) void gemm_qkv_bf16(
    const float* __restrict__ A, const float* __restrict__ W,
    const float* __restrict__ bias,
    ushort* __restrict__ Qb, ushort* __restrict__ Kb, ushort* __restrict__ Vtb)
{
  __shared__ float As[16][68];
  __shared__ float Ws[16][68];
  const int bm = blockIdx.y * 64;
  const int bn = blockIdx.x * 64;
  const int tid = threadIdx.x;
  const int tm = tid >> 4, tn = tid & 15;
  const int lr = tid >> 2;
  const int lk = (tid & 3) * 4;
  const int K = D;
  const float* Ap = A + (size_t)(bm + lr) * K + lk;
  const float* Wp = W + (size_t)(bn + lr) * K + lk;
  float acc[4][4] = {};
  for (int k0 = 0; k0 < K; k0 += 16) {
    float4 a4 = *(const float4*)(Ap + k0);
    float4 w4 = *(const float4*)(Wp + k0);
    __syncthreads();
    As[lk + 0][lr] = a4.x; As[lk + 1][lr] = a4.y; As[lk + 2][lr] = a4.z; As[lk + 3][lr] = a4.w;
    Ws[lk + 0][lr] = w4.x; Ws[lk + 1][lr] = w4.y; Ws[lk + 2][lr] = w4.z; Ws[lk + 3][lr] = w4.w;
    __syncthreads();
#pragma unroll
    for (int kk = 0; kk < 16; kk++) {
      const float4 a = *(const float4*)&As[kk][tm * 4];
      const float4 b = *(const float4*)&Ws[kk][tn * 4];
      acc[0][0] += a.x * b.x; acc[0][1] += a.x * b.y; acc[0][2] += a.x * b.z; acc[0][3] += a.x * b.w;
      acc[1][0] += a.y * b.x; acc[1][1] += a.y * b.y; acc[1][2] += a.y * b.z; acc[1][3] += a.y * b.w;
      acc[2][0] += a.z * b.x; acc[2][1] += a.z * b.y; acc[2][2] += a.z * b.z; acc[2][3] += a.z * b.w;
      acc[3][0] += a.w * b.x; acc[3][1] += a.w * b.y; acc[3][2] += a.w * b.z; acc[3][3] += a.w * b.w;
    }
  }
  // add bias
#pragma unroll
  for (int i = 0; i < 4; i++)
#pragma unroll
    for (int j = 0; j < 4; j++) acc[i][j] += bias[bn + tn * 4 + j];

  const int sec = bn / D;              // 0=Q 1=K 2=V (64 | bn, so constant per block)
  const int h = (bn % D) >> 6;
  const int b = bm >> 11;
  const int tloc = (bm & (T - 1)) + tm * 4;
  if (sec < 2) {
    ushort* dst = (sec == 0 ? Qb : Kb);
#pragma unroll
    for (int i = 0; i < 4; i++) {
      uint2 u;
      u.x = (unsigned)f2bf(acc[i][0]) | ((unsigned)f2bf(acc[i][1]) << 16);
      u.y = (unsigned)f2bf(acc[i][2]) | ((unsigned)f2bf(acc[i][3]) << 16);
      *(uint2*)(dst + (((size_t)(b * H + h)) * T + tloc + i) * 64 + tn * 4) = u;
    }
  } else {
#pragma unroll
    for (int j = 0; j < 4; j++) {
      const int d = tn * 4 + j;
      uint2 u;
      u.x = (unsigned)f2bf(acc[0][j]) | ((unsigned)f2bf(acc[1][j]) << 16);
      u.y = (unsigned)f2bf(acc[2][j]) | ((unsigned)f2bf(acc[3][j]) << 16);
      *(uint2*)(Vtb + (((size_t)(b * H + h)) * 64 + d) * T + tloc) = u;
    }
  }
}

// ---------------- bf16 MFMA flash attention ----------------
// grid (B*H, T/128), 256 threads = 4 waves, wave w owns q rows [t0+32w, t0+32w+32)
__global__ __launch_bounds__(256) void attn_mfma(
    const ushort* __restrict__ Qb, const ushort* __restrict__ Kb,
    const ushort* __restrict__ Vtb, float* __restrict__ seq)
{
  const int bh = blockIdx.x;
  const int b = bh / H, h = bh % H;
  const int qb = blockIdx.y;
  const int t0 = qb * 128;
  const int tid = threadIdx.x;
  const int w = tid >> 6;
  const int l = tid & 63;
  const int l31 = l & 31;
  const int lhi = l >> 5;

  __shared__ ushort K_lds[64][72];
  __shared__ ushort V_lds[64][72];
  __shared__ ushort P_lds[4][32][72];

  bf16x8 qf[4];
  {
    const ushort* qp = Qb + ((size_t)bh * T + t0 + w * 32 + l31) * 64 + 8 * lhi;
#pragma unroll
    for (int kf = 0; kf < 4; kf++) qf[kf] = *(const bf16x8*)(qp + kf * 16);
  }
  f32x16 o0 = {0.f}, o1 = {0.f};
#pragma unroll
  for (int r = 0; r < 16; r++) { o0[r] = 0.f; o1[r] = 0.f; }
  float rs[16];
#pragma unroll
  for (int r = 0; r < 16; r++) rs[r] = 0.f;

  const int sr = tid >> 2;
  const int scg = (tid & 3) * 16;
  const ushort* ksrc = Kb + ((size_t)bh * T + sr) * 64 + scg;
  const ushort* vsrc = Vtb + ((size_t)bh * 64 + sr) * T + scg;
  const int qlo = t0 + w * 32;
  const int nt = qb * 2 + 2;

  for (int it = 0; it < nt; ++it) {
    const int s0 = it * 64;
    __syncthreads();
    {
      const bf16x8 k0 = *(const bf16x8*)(ksrc + (size_t)s0 * 64);
      const bf16x8 k1 = *(const bf16x8*)(ksrc + (size_t)s0 * 64 + 8);
      const bf16x8 v0 = *(const bf16x8*)(vsrc + s0);
      const bf16x8 v1 = *(const bf16x8*)(vsrc + s0 + 8);
      *(bf16x8*)&K_lds[sr][scg] = k0;
      *(bf16x8*)&K_lds[sr][scg + 8] = k1;
      *(bf16x8*)&V_lds[sr][scg] = v0;
      *(bf16x8*)&V_lds[sr][scg + 8] = v1;
    }
    __syncthreads();
    if (s0 > qlo + 31) continue;      // fully masked for this wave (barriers stay balanced)

    // ---- S = Q K^T (two 32-col blocks) ----
    f32x16 sA, sB;
#pragma unroll
    for (int r = 0; r < 16; r++) { sA[r] = 0.f; sB[r] = 0.f; }
#pragma unroll
    for (int kf = 0; kf < 4; kf++) {
      const bf16x8 ka = *(const bf16x8*)&K_lds[l31][kf * 16 + 8 * lhi];
      const bf16x8 kb2 = *(const bf16x8*)&K_lds[32 + l31][kf * 16 + 8 * lhi];
      sA = __builtin_amdgcn_mfma_f32_32x32x16_bf16(qf[kf], ka, sA, 0, 0, 0);
      sB = __builtin_amdgcn_mfma_f32_32x32x16_bf16(qf[kf], kb2, sB, 0, 0, 0);
    }
    // ---- mask + exp + rowsum + P to LDS ----
    const bool nomask = (s0 + 63 <= qlo);
#pragma unroll
    for (int r = 0; r < 16; r++) {
      const int qrow = (r & 3) + 8 * (r >> 2) + 4 * lhi;
      const int qg = qlo + qrow;
      float pa = __expf(sA[r] * SCALE);
      float pb = __expf(sB[r] * SCALE);
      if (!nomask) {
        if (s0 + l31 > qg) pa = 0.f;
        if (s0 + 32 + l31 > qg) pb = 0.f;
      }
      rs[r] += pa + pb;
      P_lds[w][qrow][l31] = f2bf(pa);
      P_lds[w][qrow][32 + l31] = f2bf(pb);
    }
    // ---- O += P V ----
#pragma unroll
    for (int ks = 0; ks < 4; ks++) {
      const bf16x8 pf = *(const bf16x8*)&P_lds[w][l31][ks * 16 + 8 * lhi];
      const bf16x8 va = *(const bf16x8*)&V_lds[l31][ks * 16 + 8 * lhi];
      const bf16x8 vb = *(const bf16x8*)&V_lds[32 + l31][ks * 16 + 8 * lhi];
      o0 = __builtin_amdgcn_mfma_f32_32x32x16_bf16(pf, va, o0, 0, 0, 0);
      o1 = __builtin_amdgcn_mfma_f32_32x32x16_bf16(pf, vb, o1, 0, 0, 0);
    }
  }

#pragma unroll
  for (int r = 0; r < 16; r++) {
    float v = rs[r];
    v += __shfl_xor(v, 1); v += __shfl_xor(v, 2); v += __shfl_xor(v, 4);
    v += __shfl_xor(v, 8); v += __shfl_xor(v, 16);
    rs[r] = 1.f / v;
  }
  float* op = seq + ((size_t)b * T + qlo) * D + h * 64 + l31;
#pragma unroll
  for (int r = 0; r < 16; r++) {
    const int qrow = (r & 3) + 8 * (r >> 2) + 4 * lhi;
    op[(size_t)qrow * D] = o0[r] * rs[r];
    op[(size_t)qrow * D + 32] = o1[r] * rs[r];
  }
}

// ---------------- Plucker memory: chunked decay scan ----------------
__device__ __forceinline__ void ext_norm6(const float4 a, const float4 b, float* L)
{
  L[0] = a.x * b.y - a.y * b.x;
  L[1] = a.x * b.z - a.z * b.x;
  L[2] = a.x * b.w - a.w * b.x;
  L[3] = a.y * b.z - a.z * b.y;
  L[4] = a.y * b.w - a.w * b.y;
  L[5] = a.z * b.w - a.w * b.z;
  float n2 = L[0]*L[0] + L[1]*L[1] + L[2]*L[2] + L[3]*L[3] + L[4]*L[4] + L[5]*L[5];
  float n = fmaxf(sqrtf(n2), 1e-12f);
  float inv = 1.f / n;
#pragma unroll
  for (int i = 0; i < 6; i++) L[i] *= inv;
}

__global__ __launch_bounds__(256) void memscan(
    const float* __restrict__ xw1w, const float* __restrict__ xw2w,
    const float* __restrict__ xw1r, const float* __restrict__ xw2r,
    const float* __restrict__ memg, const float* __restrict__ mem_scale,
    float* __restrict__ gated)
{
  const int b = blockIdx.x / H, h = blockIdx.x % H;
  const int tid = threadIdx.x;
  __shared__ float S[256][22];
  const int base = tid * 8;
  const size_t rb = (size_t)b * T;

  float M[21];
#pragma unroll
  for (int c = 0; c < 21; c++) M[c] = 0.f;
  float sloc[8];

  for (int j = 0; j < 8; j++) {
    const int t = base + j;
    const float4 w2 = *(const float4*)(xw2w + (rb + t) * 48 + h * 4);
    float C[21];
#pragma unroll
    for (int c = 0; c < 21; c++) C[c] = 0.f;
    const int offs[4] = {1, 2, 4, 8};
#pragma unroll
    for (int oi = 0; oi < 4; oi++) {
      const int off = offs[oi];
      if (t >= off) {
        const float4 w1 = *(const float4*)(xw1w + (rb + t - off) * 48 + h * 4);
        float L[6];
        ext_norm6(w1, w2, L);
        const float Jv[6] = { L[5], -L[4], L[3], L[2], -L[1], L[0] };
        int c = 0;
#pragma unroll
        for (int p = 0; p < 6; p++)
#pragma unroll
          for (int q = p; q < 6; q++) { C[c] += Jv[p] * Jv[q]; c++; }
      }
    }
    float R[6];
    {
      const float4 r1 = *(const float4*)(xw1r + (rb + t) * 48 + h * 4);
      const float4 r2 = *(const float4*)(xw2r + (rb + t) * 48 + h * 4);
      ext_norm6(r1, r2, R);
    }
    float qd = 0.f;
    {
      int c = 0;
#pragma unroll
      for (int p = 0; p < 6; p++) {
        qd += M[c] * R[p] * R[p]; c++;
#pragma unroll
        for (int q = p + 1; q < 6; q++) { qd += 2.f * M[c] * R[p] * R[q]; c++; }
      }
    }
    sloc[j] = qd;
#pragma unroll
    for (int cc = 0; cc < 21; cc++) M[cc] = DECAY_F * (M[cc] + C[cc]);
  }

#pragma unroll
  for (int c = 0; c < 21; c++) S[tid][c] = M[c];
  __syncthreads();
  if (tid < 21) {
    float pv = 0.f;
    const float d8 = 0.92274469442792013f;  // 0.99^8
    for (int i = 0; i < 256; i++) {
      float a = S[i][tid];
      S[i][tid] = pv;
      pv = d8 * pv + a;
    }
  }
  __syncthreads();
  float P[21];
#pragma unroll
  for (int c = 0; c < 21; c++) P[c] = S[tid][c];

  const float msc = mem_scale[h];
  float dj = 1.f;
  for (int j = 0; j < 8; j++) {
    const int t = base + j;
    float R[6];
    {
      const float4 r1 = *(const float4*)(xw1r + (rb + t) * 48 + h * 4);
      const float4 r2 = *(const float4*)(xw2r + (rb + t) * 48 + h * 4);
      ext_norm6(r1, r2, R);
    }
    float qd = 0.f;
    {
      int c = 0;
#pragma unroll
      for (int p = 0; p < 6; p++) {
        qd += P[c] * R[p] * R[p]; c++;
#pragma unroll
        for (int q = p + 1; q < 6; q++) { qd += 2.f * P[c] * R[p] * R[q]; c++; }
      }
    }
    const float score = (sloc[j] + dj * qd) * 0.25f;
    const float g1 = 1.f / (1.f + __expf(-score * msc));
    const float graw = memg[(rb + t) * H + h];
    const float g2 = 1.f / (1.f + __expf(-graw));
    atomicAdd(&gated[rb + t], g1 * g2 * (1.f / 12.f));
    dj *= DECAY_F;
  }
}

// ---------------- z = seq + gated * memv ----------------
__global__ void fuse_z(const float* __restrict__ seq, const float* __restrict__ memv,
                       const float* __restrict__ gated, float* __restrict__ z)
{
  const int row = blockIdx.x;
  const int c4 = threadIdx.x;
  const float g = gated[row];
  const float4 s4 = *(const float4*)(seq + (size_t)row * D + c4 * 4);
  const float4 m4 = *(const float4*)(memv + (size_t)row * D + c4 * 4);
  float4 o;
  o.x = s4.x + g * m4.x; o.y = s4.y + g * m4.y;
  o.z = s4.z + g * m4.z; o.w = s4.w + g * m4.w;
  *(float4*)(z + (size_t)row * D + c4 * 4) = o;
}

extern "C" void kernel_launch(void* const* d_in, const int* in_sizes, int n_in,
                              void* d_out, int out_size, void* d_ws, size_t ws_size,
                              hipStream_t stream)
{
  const float* x      = (const float*)d_in[0];
  const float* qkv_w  = (const float*)d_in[1];
  const float* qkv_b  = (const float*)d_in[2];
  const float* w1w    = (const float*)d_in[3];
  const float* w2w    = (const float*)d_in[4];
  const float* w1r    = (const float*)d_in[5];
  const float* w2r    = (const float*)d_in[6];
  const float* memv_w = (const float*)d_in[7];
  const float* memv_b = (const float*)d_in[8];
  const float* memg_w = (const float*)d_in[9];
  const float* memg_b = (const float*)d_in[10];
  const float* mem_scale = (const float*)d_in[11];
  const float* out_w  = (const float*)d_in[12];
  const float* out_b  = (const float*)d_in[13];
  float* out = (float*)d_out;

  float* ws   = (float*)d_ws;
  float* seq  = ws;                               // [NBT, 768]
  float* memv = seq  + (size_t)NBT * D;           // [NBT, 768]
  float* zbuf = memv + (size_t)NBT * D;           // [NBT, 768]
  float* memg = zbuf + (size_t)NBT * D;           // [NBT, 12]
  float* xw1w = memg + (size_t)NBT * H;           // [NBT, 48]
  float* xw2w = xw1w + (size_t)NBT * 48;
  float* xw1r = xw2w + (size_t)NBT * 48;
  float* xw2r = xw1r + (size_t)NBT * 48;
  float* gated = xw2r + (size_t)NBT * 48;         // [NBT]
  ushort* Qb  = (ushort*)(gated + NBT);           // [B*H][T][64]
  ushort* Kb  = Qb + (size_t)24 * T * 64;
  ushort* Vtb = Kb + (size_t)24 * T * 64;         // [B*H][64][T]

  dim3 blk(256);
  gemm_qkv_bf16<<<dim3(36, 64), blk, 0, stream>>>(x, qkv_w, qkv_b, Qb, Kb, Vtb);
  gemm64<<<dim3(12, 64), blk, 0, stream>>>(x, memv_w, memv_b, memv, D, D, D);
  gemm64<<<dim3(1, 64),  blk, 0, stream>>>(x, memg_w, memg_b, memg, H, D, H);
  gemm64<<<dim3(1, 64),  blk, 0, stream>>>(x, w1w, nullptr, xw1w, 48, D, 48);
  gemm64<<<dim3(1, 64),  blk, 0, stream>>>(x, w2w, nullptr, xw2w, 48, D, 48);
  gemm64<<<dim3(1, 64),  blk, 0, stream>>>(x, w1r, nullptr, xw1r, 48, D, 48);
  gemm64<<<dim3(1, 64),  blk, 0, stream>>>(x, w2r, nullptr, xw2r, 48, D, 48);

  attn_mfma<<<dim3(2 * H, T / 128), blk, 0, stream>>>(Qb, Kb, Vtb, seq);

  hipMemsetAsync(gated, 0, NBT * sizeof(float), stream);
  memscan<<<dim3(2 * H), blk, 0, stream>>>(xw1w, xw2w, xw1r, xw2r, memg, mem_scale, gated);

  fuse_z<<<dim3(NBT), dim3(192), 0, stream>>>(seq, memv, gated, zbuf);
  gemm64<<<dim3(12, 64), blk, 0, stream>>>(zbuf, out_w, out_b, out, D, D, D);
}

// Round 3
// 220.320 us; speedup vs baseline: 8.1136x; 3.0228x over previous
//
#include <hip/hip_runtime.h>

#define H 12
#define T 2048
#define D 768
#define NBT 4096            // B*T
#define SCALE 0.125f
#define DECAY_F 0.99f

typedef __attribute__((ext_vector_type(8))) short bf16x8;
typedef __attribute__((ext_vector_type(4))) float f32x4;
typedef __attribute__((ext_vector_type(16))) float f32x16;

static __device__ __forceinline__ ushort f2bf(float f) {
  union { float f; unsigned u; } v; v.f = f;
  unsigned r = (v.u + 0x7FFFu + ((v.u >> 16) & 1u)) >> 16;
  return (ushort)r;
}

static __device__ __forceinline__ void gload16(const void* g, void* s) {
  __builtin_amdgcn_global_load_lds(
      (const __attribute__((address_space(1))) unsigned int*)g,
      (__attribute__((address_space(3))) unsigned int*)s, 16, 0, 0);
}

// ---------------- cast x + all weights to bf16 (flat segmented) ----------
// dst layout: [Xb: 4096*768][Wb: qkv 2304 | memv 768 | out 768 | w1w 48 | w2w 48
//              | w1r 48 | w2r 48 | memg 12 | zero-pad 52 rows]  (rows of 768)
__global__ __launch_bounds__(256) void cast_all(
    const float* __restrict__ x, const float* __restrict__ qkv_w,
    const float* __restrict__ memv_w, const float* __restrict__ out_w,
    const float* __restrict__ w1w, const float* __restrict__ w2w,
    const float* __restrict__ w1r, const float* __restrict__ w2r,
    const float* __restrict__ memg_w, ushort* __restrict__ dst)
{
  const size_t i8 = ((size_t)blockIdx.x * 256 + threadIdx.x) * 8;
  const float* src; size_t off;
  if      (i8 < 3145728) { src = x;      off = i8; }
  else if (i8 < 4915200) { src = qkv_w;  off = i8 - 3145728; }
  else if (i8 < 5505024) { src = memv_w; off = i8 - 4915200; }
  else if (i8 < 6094848) { src = out_w;  off = i8 - 5505024; }
  else if (i8 < 6131712) { src = w1w;    off = i8 - 6094848; }
  else if (i8 < 6168576) { src = w2w;    off = i8 - 6131712; }
  else if (i8 < 6205440) { src = w1r;    off = i8 - 6168576; }
  else if (i8 < 6242304) { src = w2r;    off = i8 - 6205440; }
  else if (i8 < 6251520) { src = memg_w; off = i8 - 6242304; }
  else { *(uint4*)(dst + i8) = make_uint4(0, 0, 0, 0); return; }
  const float4 a = *(const float4*)(src + off);
  const float4 b = *(const float4*)(src + off + 4);
  bf16x8 o;
  o[0] = (short)f2bf(a.x); o[1] = (short)f2bf(a.y);
  o[2] = (short)f2bf(a.z); o[3] = (short)f2bf(a.w);
  o[4] = (short)f2bf(b.x); o[5] = (short)f2bf(b.y);
  o[6] = (short)f2bf(b.z); o[7] = (short)f2bf(b.w);
  *(bf16x8*)(dst + i8) = o;
}

// ---------------- bf16 MFMA GEMM: C[M,N] = A[M,768] @ W[N,768]^T ----------
// 128x128 tile, BK=64, 4 waves (2x2), 4x4 16x16x32 fragments per wave.
// MODE 0: fp32 C + optional bias (N bounds-checked)
// MODE 1: qkv epilogue -> Qb/Kb [bh][t][64] bf16, Vtb [bh][64][t] bf16
template<int MODE>
__global__ __launch_bounds__(256) void gemm_mfma(
    const ushort* __restrict__ A, const ushort* __restrict__ W,
    const float* __restrict__ bias, float* __restrict__ C, int N, int ldc,
    ushort* __restrict__ Qb, ushort* __restrict__ Kb, ushort* __restrict__ Vtb)
{
  __shared__ ushort A_lds[128 * 64];
  __shared__ ushort B_lds[128 * 64];
  const int tid = threadIdx.x;
  const int w = tid >> 6, l = tid & 63;
  const int wm = w >> 1, wn = w & 1;
  const int bm = blockIdx.y * 128, bn = blockIdx.x * 128;
  const int l15 = l & 15, l4 = l >> 4;

  f32x4 acc[4][4];
#pragma unroll
  for (int i = 0; i < 4; i++)
#pragma unroll
    for (int j = 0; j < 4; j++) acc[i][j] = (f32x4){0.f, 0.f, 0.f, 0.f};

  const int srow = w * 32 + (l >> 3);
  const int scol = (l & 7) * 8;
  const ushort* Ag = A + (size_t)(bm + srow) * 768 + scol;
  const ushort* Wg = W + (size_t)(bn + srow) * 768 + scol;
  ushort* Asl = &A_lds[(w * 32) * 64];
  ushort* Bsl = &B_lds[(w * 32) * 64];

  for (int k0 = 0; k0 < 768; k0 += 64) {
#pragma unroll
    for (int i = 0; i < 4; i++) {
      gload16(Ag + k0 + i * 8 * 768, Asl + i * 8 * 64);
      gload16(Wg + k0 + i * 8 * 768, Bsl + i * 8 * 64);
    }
    __syncthreads();   // drains vmcnt(0): tiles resident
#pragma unroll
    for (int ks = 0; ks < 2; ks++) {
      bf16x8 af[4], bfr[4];
#pragma unroll
      for (int i = 0; i < 4; i++) {
        af[i]  = *(const bf16x8*)&A_lds[(wm * 64 + i * 16 + l15) * 64 + ks * 32 + l4 * 8];
        bfr[i] = *(const bf16x8*)&B_lds[(wn * 64 + i * 16 + l15) * 64 + ks * 32 + l4 * 8];
      }
#pragma unroll
      for (int mi = 0; mi < 4; mi++)
#pragma unroll
        for (int ni = 0; ni < 4; ni++)
          acc[mi][ni] = __builtin_amdgcn_mfma_f32_16x16x32_bf16(af[mi], bfr[ni], acc[mi][ni], 0, 0, 0);
    }
    __syncthreads();   // all reads done before next stage overwrites
  }

  if (MODE == 0) {
#pragma unroll
    for (int mi = 0; mi < 4; mi++) {
      const int row0 = bm + wm * 64 + mi * 16 + l4 * 4;
#pragma unroll
      for (int ni = 0; ni < 4; ni++) {
        const int col = bn + wn * 64 + ni * 16 + l15;
        if (col < N) {
          const float bv = bias ? bias[col] : 0.f;
#pragma unroll
          for (int r = 0; r < 4; r++)
            C[(size_t)(row0 + r) * ldc + col] = acc[mi][ni][r] + bv;
        }
      }
    }
  } else {
#pragma unroll
    for (int mi = 0; mi < 4; mi++) {
      const int row0 = bm + wm * 64 + mi * 16 + l4 * 4;
      const int b = row0 >> 11, tl = row0 & (T - 1);
#pragma unroll
      for (int ni = 0; ni < 4; ni++) {
        const int col = bn + wn * 64 + ni * 16 + l15;
        const float bv = bias[col];
        const int sec = col / 768, cm = col % 768;
        const int h = cm >> 6, d = cm & 63;
        if (sec < 2) {
          ushort* dst = sec ? Kb : Qb;
#pragma unroll
          for (int r = 0; r < 4; r++)
            dst[((size_t)(b * H + h) * T + tl + r) * 64 + d] = f2bf(acc[mi][ni][r] + bv);
        } else {
          uint2 u;
          u.x = (unsigned)f2bf(acc[mi][ni][0] + bv) | ((unsigned)f2bf(acc[mi][ni][1] + bv) << 16);
          u.y = (unsigned)f2bf(acc[mi][ni][2] + bv) | ((unsigned)f2bf(acc[mi][ni][3] + bv) << 16);
          *(uint2*)(Vtb + ((size_t)(b * H + h) * 64 + d) * T + tl) = u;
        }
      }
    }
  }
}

// ---------------- bf16 MFMA flash attention ----------------
__global__ __launch_bounds__(256) void attn_mfma(
    const ushort* __restrict__ Qb, const ushort* __restrict__ Kb,
    const ushort* __restrict__ Vtb, float* __restrict__ seq)
{
  const int bh = blockIdx.x;
  const int b = bh / H, h = bh % H;
  const int qb = blockIdx.y;
  const int t0 = qb * 128;
  const int tid = threadIdx.x;
  const int w = tid >> 6;
  const int l = tid & 63;
  const int l31 = l & 31;
  const int lhi = l >> 5;

  __shared__ ushort K_lds[64][72];
  __shared__ ushort V_lds[64][72];
  __shared__ ushort P_lds[4][32][72];

  bf16x8 qf[4];
  {
    const ushort* qp = Qb + ((size_t)bh * T + t0 + w * 32 + l31) * 64 + 8 * lhi;
#pragma unroll
    for (int kf = 0; kf < 4; kf++) qf[kf] = *(const bf16x8*)(qp + kf * 16);
  }
  f32x16 o0, o1;
#pragma unroll
  for (int r = 0; r < 16; r++) { o0[r] = 0.f; o1[r] = 0.f; }
  float rs[16];
#pragma unroll
  for (int r = 0; r < 16; r++) rs[r] = 0.f;

  const int sr = tid >> 2;
  const int scg = (tid & 3) * 16;
  const ushort* ksrc = Kb + ((size_t)bh * T + sr) * 64 + scg;
  const ushort* vsrc = Vtb + ((size_t)bh * 64 + sr) * T + scg;
  const int qlo = t0 + w * 32;
  const int nt = qb * 2 + 2;

  for (int it = 0; it < nt; ++it) {
    const int s0 = it * 64;
    __syncthreads();
    {
      const bf16x8 k0 = *(const bf16x8*)(ksrc + (size_t)s0 * 64);
      const bf16x8 k1 = *(const bf16x8*)(ksrc + (size_t)s0 * 64 + 8);
      const bf16x8 v0 = *(const bf16x8*)(vsrc + s0);
      const bf16x8 v1 = *(const bf16x8*)(vsrc + s0 + 8);
      *(bf16x8*)&K_lds[sr][scg] = k0;
      *(bf16x8*)&K_lds[sr][scg + 8] = k1;
      *(bf16x8*)&V_lds[sr][scg] = v0;
      *(bf16x8*)&V_lds[sr][scg + 8] = v1;
    }
    __syncthreads();
    if (s0 > qlo + 31) continue;      // fully masked for this wave

    f32x16 sA, sB;
#pragma unroll
    for (int r = 0; r < 16; r++) { sA[r] = 0.f; sB[r] = 0.f; }
#pragma unroll
    for (int kf = 0; kf < 4; kf++) {
      const bf16x8 ka = *(const bf16x8*)&K_lds[l31][kf * 16 + 8 * lhi];
      const bf16x8 kb2 = *(const bf16x8*)&K_lds[32 + l31][kf * 16 + 8 * lhi];
      sA = __builtin_amdgcn_mfma_f32_32x32x16_bf16(qf[kf], ka, sA, 0, 0, 0);
      sB = __builtin_amdgcn_mfma_f32_32x32x16_bf16(qf[kf], kb2, sB, 0, 0, 0);
    }
    const bool nomask = (s0 + 63 <= qlo);
#pragma unroll
    for (int r = 0; r < 16; r++) {
      const int qrow = (r & 3) + 8 * (r >> 2) + 4 * lhi;
      const int qg = qlo + qrow;
      float pa = __expf(sA[r] * SCALE);
      float pb = __expf(sB[r] * SCALE);
      if (!nomask) {
        if (s0 + l31 > qg) pa = 0.f;
        if (s0 + 32 + l31 > qg) pb = 0.f;
      }
      rs[r] += pa + pb;
      P_lds[w][qrow][l31] = f2bf(pa);
      P_lds[w][qrow][32 + l31] = f2bf(pb);
    }
#pragma unroll
    for (int ks = 0; ks < 4; ks++) {
      const bf16x8 pf = *(const bf16x8*)&P_lds[w][l31][ks * 16 + 8 * lhi];
      const bf16x8 va = *(const bf16x8*)&V_lds[l31][ks * 16 + 8 * lhi];
      const bf16x8 vb = *(const bf16x8*)&V_lds[32 + l31][ks * 16 + 8 * lhi];
      o0 = __builtin_amdgcn_mfma_f32_32x32x16_bf16(pf, va, o0, 0, 0, 0);
      o1 = __builtin_amdgcn_mfma_f32_32x32x16_bf16(pf, vb, o1, 0, 0, 0);
    }
  }

#pragma unroll
  for (int r = 0; r < 16; r++) {
    float v = rs[r];
    v += __shfl_xor(v, 1); v += __shfl_xor(v, 2); v += __shfl_xor(v, 4);
    v += __shfl_xor(v, 8); v += __shfl_xor(v, 16);
    rs[r] = 1.f / v;
  }
  float* op = seq + ((size_t)b * T + qlo) * D + h * 64 + l31;
#pragma unroll
  for (int r = 0; r < 16; r++) {
    const int qrow = (r & 3) + 8 * (r >> 2) + 4 * lhi;
    op[(size_t)qrow * D] = o0[r] * rs[r];
    op[(size_t)qrow * D + 32] = o1[r] * rs[r];
  }
}

// ---------------- Plucker memory: chunked decay scan ----------------
__device__ __forceinline__ void ext_norm6(const float4 a, const float4 b, float* L)
{
  L[0] = a.x * b.y - a.y * b.x;
  L[1] = a.x * b.z - a.z * b.x;
  L[2] = a.x * b.w - a.w * b.x;
  L[3] = a.y * b.z - a.z * b.y;
  L[4] = a.y * b.w - a.w * b.y;
  L[5] = a.z * b.w - a.w * b.z;
  float n2 = L[0]*L[0] + L[1]*L[1] + L[2]*L[2] + L[3]*L[3] + L[4]*L[4] + L[5]*L[5];
  float n = fmaxf(sqrtf(n2), 1e-12f);
  float inv = 1.f / n;
#pragma unroll
  for (int i = 0; i < 6; i++) L[i] *= inv;
}

#define PLDC 204
// proj layout per row: [w1w:0..47 | w2w:48..95 | w1r:96..143 | w2r:144..191 | memg:192..203]
__global__ __launch_bounds__(256) void memscan(
    const float* __restrict__ proj, const float* __restrict__ memg_b,
    const float* __restrict__ mem_scale, float* __restrict__ gated)
{
  const int b = blockIdx.x / H, h = blockIdx.x % H;
  const int tid = threadIdx.x;
  __shared__ float S[256][22];
  const int base = tid * 8;
  const size_t rb = (size_t)b * T;

  float M[21];
#pragma unroll
  for (int c = 0; c < 21; c++) M[c] = 0.f;
  float sloc[8];

  for (int j = 0; j < 8; j++) {
    const int t = base + j;
    const float4 w2 = *(const float4*)(proj + (rb + t) * PLDC + 48 + h * 4);
    float C[21];
#pragma unroll
    for (int c = 0; c < 21; c++) C[c] = 0.f;
    const int offs[4] = {1, 2, 4, 8};
#pragma unroll
    for (int oi = 0; oi < 4; oi++) {
      const int off = offs[oi];
      if (t >= off) {
        const float4 w1 = *(const float4*)(proj + (rb + t - off) * PLDC + 0 + h * 4);
        float L[6];
        ext_norm6(w1, w2, L);
        const float Jv[6] = { L[5], -L[4], L[3], L[2], -L[1], L[0] };
        int c = 0;
#pragma unroll
        for (int p = 0; p < 6; p++)
#pragma unroll
          for (int q = p; q < 6; q++) { C[c] += Jv[p] * Jv[q]; c++; }
      }
    }
    float R[6];
    {
      const float4 r1 = *(const float4*)(proj + (rb + t) * PLDC + 96 + h * 4);
      const float4 r2 = *(const float4*)(proj + (rb + t) * PLDC + 144 + h * 4);
      ext_norm6(r1, r2, R);
    }
    float qd = 0.f;
    {
      int c = 0;
#pragma unroll
      for (int p = 0; p < 6; p++) {
        qd += M[c] * R[p] * R[p]; c++;
#pragma unroll
        for (int q = p + 1; q < 6; q++) { qd += 2.f * M[c] * R[p] * R[q]; c++; }
      }
    }
    sloc[j] = qd;
#pragma unroll
    for (int cc = 0; cc < 21; cc++) M[cc] = DECAY_F * (M[cc] + C[cc]);
  }

#pragma unroll
  for (int c = 0; c < 21; c++) S[tid][c] = M[c];
  __syncthreads();
  if (tid < 21) {
    float pv = 0.f;
    const float d8 = 0.92274469442792013f;  // 0.99^8
    for (int i = 0; i < 256; i++) {
      float a = S[i][tid];
      S[i][tid] = pv;
      pv = d8 * pv + a;
    }
  }
  __syncthreads();
  float P[21];
#pragma unroll
  for (int c = 0; c < 21; c++) P[c] = S[tid][c];

  const float msc = mem_scale[h];
  const float gb = memg_b[h];
  float dj = 1.f;
  for (int j = 0; j < 8; j++) {
    const int t = base + j;
    float R[6];
    {
      const float4 r1 = *(const float4*)(proj + (rb + t) * PLDC + 96 + h * 4);
      const float4 r2 = *(const float4*)(proj + (rb + t) * PLDC + 144 + h * 4);
      ext_norm6(r1, r2, R);
    }
    float qd = 0.f;
    {
      int c = 0;
#pragma unroll
      for (int p = 0; p < 6; p++) {
        qd += P[c] * R[p] * R[p]; c++;
#pragma unroll
        for (int q = p + 1; q < 6; q++) { qd += 2.f * P[c] * R[p] * R[q]; c++; }
      }
    }
    const float score = (sloc[j] + dj * qd) * 0.25f;
    const float g1 = 1.f / (1.f + __expf(-score * msc));
    const float graw = proj[(rb + t) * PLDC + 192 + h] + gb;
    const float g2 = 1.f / (1.f + __expf(-graw));
    atomicAdd(&gated[rb + t], g1 * g2 * (1.f / 12.f));
    dj *= DECAY_F;
  }
}

// ---------------- z = seq + gated * memv  (bf16 out for final GEMM) ------
__global__ __launch_bounds__(256) void fuse_z(
    const float* __restrict__ seq, const float* __restrict__ memv,
    const float* __restrict__ gated, ushort* __restrict__ zb)
{
  const int idx = blockIdx.x * 256 + threadIdx.x;
  const int row = idx / 96, c = (idx % 96) * 8;
  const float g = gated[row];
  const float4 s0 = *(const float4*)(seq + (size_t)row * D + c);
  const float4 s1 = *(const float4*)(seq + (size_t)row * D + c + 4);
  const float4 m0 = *(const float4*)(memv + (size_t)row * D + c);
  const float4 m1 = *(const float4*)(memv + (size_t)row * D + c + 4);
  bf16x8 o;
  o[0] = (short)f2bf(s0.x + g * m0.x); o[1] = (short)f2bf(s0.y + g * m0.y);
  o[2] = (short)f2bf(s0.z + g * m0.z); o[3] = (short)f2bf(s0.w + g * m0.w);
  o[4] = (short)f2bf(s1.x + g * m1.x); o[5] = (short)f2bf(s1.y + g * m1.y);
  o[6] = (short)f2bf(s1.z + g * m1.z); o[7] = (short)f2bf(s1.w + g * m1.w);
  *(bf16x8*)(zb + (size_t)row * D + c) = o;
}

extern "C" void kernel_launch(void* const* d_in, const int* in_sizes, int n_in,
                              void* d_out, int out_size, void* d_ws, size_t ws_size,
                              hipStream_t stream)
{
  const float* x      = (const float*)d_in[0];
  const float* qkv_w  = (const float*)d_in[1];
  const float* qkv_b  = (const float*)d_in[2];
  const float* w1w    = (const float*)d_in[3];
  const float* w2w    = (const float*)d_in[4];
  const float* w1r    = (const float*)d_in[5];
  const float* w2r    = (const float*)d_in[6];
  const float* memv_w = (const float*)d_in[7];
  const float* memv_b = (const float*)d_in[8];
  const float* memg_w = (const float*)d_in[9];
  const float* memg_b = (const float*)d_in[10];
  const float* mem_scale = (const float*)d_in[11];
  const float* out_w  = (const float*)d_in[12];
  const float* out_b  = (const float*)d_in[13];
  float* out = (float*)d_out;

  float* ws   = (float*)d_ws;
  float* seq  = ws;                               // [4096][768] f32
  float* memv = seq  + (size_t)NBT * D;           // [4096][768] f32
  float* proj = memv + (size_t)NBT * D;           // [4096][204] f32
  float* gated = proj + (size_t)NBT * PLDC;       // [4096]
  ushort* Xb  = (ushort*)(gated + NBT);           // [4096][768] bf16
  ushort* Wb  = Xb + (size_t)NBT * D;             // [4096][768] bf16 (see cast_all)
  ushort* Qb  = Wb + (size_t)NBT * D;             // [24][2048][64]
  ushort* Kb  = Qb + (size_t)24 * T * 64;
  ushort* Vtb = Kb + (size_t)24 * T * 64;         // [24][64][2048]
  ushort* zb  = Vtb + (size_t)24 * T * 64;        // [4096][768] bf16

  const ushort* W_qkv  = Wb;
  const ushort* W_memv = Wb + (size_t)2304 * 768;
  const ushort* W_out  = Wb + (size_t)(2304 + 768) * 768;
  const ushort* W_proj = Wb + (size_t)(2304 + 768 + 768) * 768;

  dim3 blk(256);
  cast_all<<<dim3(3072), blk, 0, stream>>>(x, qkv_w, memv_w, out_w,
                                           w1w, w2w, w1r, w2r, memg_w, Xb);

  gemm_mfma<1><<<dim3(18, 32), blk, 0, stream>>>(Xb, W_qkv, qkv_b, nullptr,
                                                 2304, 0, Qb, Kb, Vtb);
  gemm_mfma<0><<<dim3(6, 32), blk, 0, stream>>>(Xb, W_memv, memv_b, memv,
                                                768, 768, nullptr, nullptr, nullptr);
  gemm_mfma<0><<<dim3(2, 32), blk, 0, stream>>>(Xb, W_proj, nullptr, proj,
                                                PLDC, PLDC, nullptr, nullptr, nullptr);

  attn_mfma<<<dim3(2 * H, T / 128), blk, 0, stream>>>(Qb, Kb, Vtb, seq);

  hipMemsetAsync(gated, 0, NBT * sizeof(float), stream);
  memscan<<<dim3(2 * H), blk, 0, stream>>>(proj, memg_b, mem_scale, gated);

  fuse_z<<<dim3(NBT * 96 / 256), blk, 0, stream>>>(seq, memv, gated, zb);
  gemm_mfma<0><<<dim3(6, 32), blk, 0, stream>>>(zb, W_out, out_b, out,
                                                768, 768, nullptr, nullptr, nullptr);
}

// Round 4
// 205.284 us; speedup vs baseline: 8.7079x; 1.0732x over previous
//
#include <hip/hip_runtime.h>

#define H 12
#define T 2048
#define D 768
#define NBT 4096            // B*T
#define SCALE 0.125f
#define DECAY_F 0.99f

typedef __attribute__((ext_vector_type(8))) short bf16x8;
typedef __attribute__((ext_vector_type(4))) float f32x4;
typedef __attribute__((ext_vector_type(16))) float f32x16;

static __device__ __forceinline__ ushort f2bf(float f) {
  union { float f; unsigned u; } v; v.f = f;
  unsigned r = (v.u + 0x7FFFu + ((v.u >> 16) & 1u)) >> 16;
  return (ushort)r;
}

static __device__ __forceinline__ void gload16(const void* g, void* s) {
  __builtin_amdgcn_global_load_lds(
      (const __attribute__((address_space(1))) unsigned int*)g,
      (__attribute__((address_space(3))) unsigned int*)s, 16, 0, 0);
}

// ---------------- cast x + all weights to bf16 (flat segmented) ----------
// dst rows (768 wide): [x:4096 | qkv:2304 | memv:768 | w1w:48 | w2w:48 | w1r:48
//                       | w2r:48 | memg:12 | pad:52 | out:768]
__global__ __launch_bounds__(256) void cast_all(
    const float* __restrict__ x, const float* __restrict__ qkv_w,
    const float* __restrict__ memv_w, const float* __restrict__ out_w,
    const float* __restrict__ w1w, const float* __restrict__ w2w,
    const float* __restrict__ w1r, const float* __restrict__ w2r,
    const float* __restrict__ memg_w, ushort* __restrict__ dst)
{
  const size_t i8 = ((size_t)blockIdx.x * 256 + threadIdx.x) * 8;
  const float* src; size_t off;
  if      (i8 < 3145728) { src = x;      off = i8; }
  else if (i8 < 4915200) { src = qkv_w;  off = i8 - 3145728; }
  else if (i8 < 5505024) { src = memv_w; off = i8 - 4915200; }
  else if (i8 < 5541888) { src = w1w;    off = i8 - 5505024; }
  else if (i8 < 5578752) { src = w2w;    off = i8 - 5541888; }
  else if (i8 < 5615616) { src = w1r;    off = i8 - 5578752; }
  else if (i8 < 5652480) { src = w2r;    off = i8 - 5615616; }
  else if (i8 < 5661696) { src = memg_w; off = i8 - 5652480; }
  else if (i8 < 5701632) { *(uint4*)(dst + i8) = make_uint4(0, 0, 0, 0); return; }
  else                   { src = out_w;  off = i8 - 5701632; }
  const float4 a = *(const float4*)(src + off);
  const float4 b = *(const float4*)(src + off + 4);
  bf16x8 o;
  o[0] = (short)f2bf(a.x); o[1] = (short)f2bf(a.y);
  o[2] = (short)f2bf(a.z); o[3] = (short)f2bf(a.w);
  o[4] = (short)f2bf(b.x); o[5] = (short)f2bf(b.y);
  o[6] = (short)f2bf(b.z); o[7] = (short)f2bf(b.w);
  *(bf16x8*)(dst + i8) = o;
}

// ---------------- bf16 MFMA GEMM: C = A[M,768] @ W[N,768]^T ---------------
// 128x128 tile, BK=64, 4 waves (2x2), 4x4 16x16x32 fragments per wave.
// MODE 0: fp32 C + bias (out-GEMM)
// MODE 1: mega epilogue: col<2304 qkv->Qb/Kb/Vtb; <3072 memv f32; <3276 proj f32
template<int MODE>
__global__ __launch_bounds__(256) void gemm_mfma(
    const ushort* __restrict__ A, const ushort* __restrict__ W,
    const float* __restrict__ bias, float* __restrict__ C, int ldc,
    const float* __restrict__ memv_b, float* __restrict__ memvp,
    float* __restrict__ projp,
    ushort* __restrict__ Qb, ushort* __restrict__ Kb, ushort* __restrict__ Vtb)
{
  __shared__ ushort A_lds[128 * 64];
  __shared__ ushort B_lds[128 * 64];
  const int tid = threadIdx.x;
  const int w = tid >> 6, l = tid & 63;
  const int wm = w >> 1, wn = w & 1;
  const int bm = blockIdx.y * 128, bn = blockIdx.x * 128;
  const int l15 = l & 15, l4 = l >> 4;

  f32x4 acc[4][4];
#pragma unroll
  for (int i = 0; i < 4; i++)
#pragma unroll
    for (int j = 0; j < 4; j++) acc[i][j] = (f32x4){0.f, 0.f, 0.f, 0.f};

  const int srow = w * 32 + (l >> 3);
  const int scol = (l & 7) * 8;
  const ushort* Ag = A + (size_t)(bm + srow) * 768 + scol;
  const ushort* Wg = W + (size_t)(bn + srow) * 768 + scol;
  ushort* Asl = &A_lds[(w * 32) * 64];
  ushort* Bsl = &B_lds[(w * 32) * 64];

  for (int k0 = 0; k0 < 768; k0 += 64) {
#pragma unroll
    for (int i = 0; i < 4; i++) {
      gload16(Ag + k0 + i * 8 * 768, Asl + i * 8 * 64);
      gload16(Wg + k0 + i * 8 * 768, Bsl + i * 8 * 64);
    }
    __syncthreads();
#pragma unroll
    for (int ks = 0; ks < 2; ks++) {
      bf16x8 af[4], bfr[4];
#pragma unroll
      for (int i = 0; i < 4; i++) {
        af[i]  = *(const bf16x8*)&A_lds[(wm * 64 + i * 16 + l15) * 64 + ks * 32 + l4 * 8];
        bfr[i] = *(const bf16x8*)&B_lds[(wn * 64 + i * 16 + l15) * 64 + ks * 32 + l4 * 8];
      }
#pragma unroll
      for (int mi = 0; mi < 4; mi++)
#pragma unroll
        for (int ni = 0; ni < 4; ni++)
          acc[mi][ni] = __builtin_amdgcn_mfma_f32_16x16x32_bf16(af[mi], bfr[ni], acc[mi][ni], 0, 0, 0);
    }
    __syncthreads();
  }

  if (MODE == 0) {
#pragma unroll
    for (int mi = 0; mi < 4; mi++) {
      const int row0 = bm + wm * 64 + mi * 16 + l4 * 4;
#pragma unroll
      for (int ni = 0; ni < 4; ni++) {
        const int col = bn + wn * 64 + ni * 16 + l15;
        const float bv = bias[col];
#pragma unroll
        for (int r = 0; r < 4; r++)
          C[(size_t)(row0 + r) * ldc + col] = acc[mi][ni][r] + bv;
      }
    }
  } else {
#pragma unroll
    for (int mi = 0; mi < 4; mi++) {
      const int row0 = bm + wm * 64 + mi * 16 + l4 * 4;
      const int b = row0 >> 11, tl = row0 & (T - 1);
#pragma unroll
      for (int ni = 0; ni < 4; ni++) {
        const int col = bn + wn * 64 + ni * 16 + l15;
        if (col < 2304) {
          const float bv = bias[col];
          const int sec = col / 768, cm = col % 768;
          const int h = cm >> 6, d = cm & 63;
          if (sec < 2) {
            ushort* dst = sec ? Kb : Qb;
#pragma unroll
            for (int r = 0; r < 4; r++)
              dst[((size_t)(b * H + h) * T + tl + r) * 64 + d] = f2bf(acc[mi][ni][r] + bv);
          } else {
            uint2 u;
            u.x = (unsigned)f2bf(acc[mi][ni][0] + bv) | ((unsigned)f2bf(acc[mi][ni][1] + bv) << 16);
            u.y = (unsigned)f2bf(acc[mi][ni][2] + bv) | ((unsigned)f2bf(acc[mi][ni][3] + bv) << 16);
            *(uint2*)(Vtb + ((size_t)(b * H + h) * 64 + d) * T + tl) = u;
          }
        } else if (col < 3072) {
          const int c2 = col - 2304;
          const float bv = memv_b[c2];
#pragma unroll
          for (int r = 0; r < 4; r++)
            memvp[(size_t)(row0 + r) * 768 + c2] = acc[mi][ni][r] + bv;
        } else if (col < 3276) {
          const int c2 = col - 3072;
#pragma unroll
          for (int r = 0; r < 4; r++)
            projp[(size_t)(row0 + r) * 204 + c2] = acc[mi][ni][r];
        }
      }
    }
  }
}

// ---------------- bf16 MFMA flash attention, split-s with atomic merge ----
// grid: 24*72 blocks; per bh: 72 = sum over qb of ceil((qb+1)/2) s-chunks.
// Each block: q-tile qb (128 rows, 4 waves x 32), s-chunk of <=4 64-tiles.
__global__ __launch_bounds__(256) void attn_mfma(
    const ushort* __restrict__ Qb, const ushort* __restrict__ Kb,
    const ushort* __restrict__ Vtb, float* __restrict__ o_acc,
    float* __restrict__ rs_acc)
{
  const int bh = blockIdx.x / 72;
  const int b = bh / H, h = bh % H;
  int ci = blockIdx.x % 72;
  int qb = 15;
#pragma unroll
  for (int q = 0; q < 16; q++) {
    const int cnt = (q >> 1) + 1;
    if (ci < cnt) { qb = q; break; }
    ci -= cnt;
  }
  const int t0 = qb * 128;
  const int it0 = ci * 4;
  const int it1 = min(it0 + 4, 2 * qb + 2);

  const int tid = threadIdx.x;
  const int w = tid >> 6;
  const int l = tid & 63;
  const int l31 = l & 31;
  const int lhi = l >> 5;

  __shared__ ushort K_lds[64][72];
  __shared__ ushort V_lds[64][72];
  __shared__ ushort P_lds[4][32][72];

  bf16x8 qf[4];
  {
    const ushort* qp = Qb + ((size_t)bh * T + t0 + w * 32 + l31) * 64 + 8 * lhi;
#pragma unroll
    for (int kf = 0; kf < 4; kf++) qf[kf] = *(const bf16x8*)(qp + kf * 16);
  }
  f32x16 o0, o1;
#pragma unroll
  for (int r = 0; r < 16; r++) { o0[r] = 0.f; o1[r] = 0.f; }
  float rs[16];
#pragma unroll
  for (int r = 0; r < 16; r++) rs[r] = 0.f;

  const int sr = tid >> 2;
  const int scg = (tid & 3) * 16;
  const ushort* ksrc = Kb + ((size_t)bh * T + sr) * 64 + scg;
  const ushort* vsrc = Vtb + ((size_t)bh * 64 + sr) * T + scg;
  const int qlo = t0 + w * 32;

  bf16x8 kp0, kp1, vp0, vp1;
  {
    const size_t s0 = (size_t)it0 * 64;
    kp0 = *(const bf16x8*)(ksrc + s0 * 64);
    kp1 = *(const bf16x8*)(ksrc + s0 * 64 + 8);
    vp0 = *(const bf16x8*)(vsrc + s0);
    vp1 = *(const bf16x8*)(vsrc + s0 + 8);
  }

  for (int it = it0; it < it1; ++it) {
    __syncthreads();
    *(bf16x8*)&K_lds[sr][scg] = kp0;
    *(bf16x8*)&K_lds[sr][scg + 8] = kp1;
    *(bf16x8*)&V_lds[sr][scg] = vp0;
    *(bf16x8*)&V_lds[sr][scg + 8] = vp1;
    __syncthreads();
    if (it + 1 < it1) {
      const size_t s0n = (size_t)(it + 1) * 64;
      kp0 = *(const bf16x8*)(ksrc + s0n * 64);
      kp1 = *(const bf16x8*)(ksrc + s0n * 64 + 8);
      vp0 = *(const bf16x8*)(vsrc + s0n);
      vp1 = *(const bf16x8*)(vsrc + s0n + 8);
    }
    const int s0 = it * 64;
    if (s0 > qlo + 31) continue;      // fully masked for this wave

    f32x16 sA, sB;
#pragma unroll
    for (int r = 0; r < 16; r++) { sA[r] = 0.f; sB[r] = 0.f; }
#pragma unroll
    for (int kf = 0; kf < 4; kf++) {
      const bf16x8 ka = *(const bf16x8*)&K_lds[l31][kf * 16 + 8 * lhi];
      const bf16x8 kb2 = *(const bf16x8*)&K_lds[32 + l31][kf * 16 + 8 * lhi];
      sA = __builtin_amdgcn_mfma_f32_32x32x16_bf16(qf[kf], ka, sA, 0, 0, 0);
      sB = __builtin_amdgcn_mfma_f32_32x32x16_bf16(qf[kf], kb2, sB, 0, 0, 0);
    }
    const bool nomask = (s0 + 63 <= qlo);
#pragma unroll
    for (int r = 0; r < 16; r++) {
      const int qrow = (r & 3) + 8 * (r >> 2) + 4 * lhi;
      const int qg = qlo + qrow;
      float pa = __expf(sA[r] * SCALE);
      float pb = __expf(sB[r] * SCALE);
      if (!nomask) {
        if (s0 + l31 > qg) pa = 0.f;
        if (s0 + 32 + l31 > qg) pb = 0.f;
      }
      rs[r] += pa + pb;
      P_lds[w][qrow][l31] = f2bf(pa);
      P_lds[w][qrow][32 + l31] = f2bf(pb);
    }
#pragma unroll
    for (int ks = 0; ks < 4; ks++) {
      const bf16x8 pf = *(const bf16x8*)&P_lds[w][l31][ks * 16 + 8 * lhi];
      const bf16x8 va = *(const bf16x8*)&V_lds[l31][ks * 16 + 8 * lhi];
      const bf16x8 vb = *(const bf16x8*)&V_lds[32 + l31][ks * 16 + 8 * lhi];
      o0 = __builtin_amdgcn_mfma_f32_32x32x16_bf16(pf, va, o0, 0, 0, 0);
      o1 = __builtin_amdgcn_mfma_f32_32x32x16_bf16(pf, vb, o1, 0, 0, 0);
    }
  }

#pragma unroll
  for (int r = 0; r < 16; r++) {
    float v = rs[r];
    v += __shfl_xor(v, 1); v += __shfl_xor(v, 2); v += __shfl_xor(v, 4);
    v += __shfl_xor(v, 8); v += __shfl_xor(v, 16);
    rs[r] = v;
  }
  float* orow = o_acc + ((size_t)b * T + qlo) * D + h * 64 + l31;
#pragma unroll
  for (int r = 0; r < 16; r++) {
    const int qrow = (r & 3) + 8 * (r >> 2) + 4 * lhi;
    atomicAdd(orow + (size_t)qrow * D, o0[r]);
    atomicAdd(orow + (size_t)qrow * D + 32, o1[r]);
    if (l31 == 0)
      atomicAdd(&rs_acc[(size_t)(b * T + qlo + qrow) * H + h], rs[r]);
  }
}

// ---------------- Plucker memory: chunked decay scan ----------------
__device__ __forceinline__ void ext_norm6(const float4 a, const float4 b, float* L)
{
  L[0] = a.x * b.y - a.y * b.x;
  L[1] = a.x * b.z - a.z * b.x;
  L[2] = a.x * b.w - a.w * b.x;
  L[3] = a.y * b.z - a.z * b.y;
  L[4] = a.y * b.w - a.w * b.y;
  L[5] = a.z * b.w - a.w * b.z;
  float n2 = L[0]*L[0] + L[1]*L[1] + L[2]*L[2] + L[3]*L[3] + L[4]*L[4] + L[5]*L[5];
  float n = fmaxf(sqrtf(n2), 1e-12f);
  float inv = 1.f / n;
#pragma unroll
  for (int i = 0; i < 6; i++) L[i] *= inv;
}

#define PLDC 204
// proj row: [w1w:0..47 | w2w:48..95 | w1r:96..143 | w2r:144..191 | memg:192..203]
__global__ __launch_bounds__(256) void memscan(
    const float* __restrict__ proj, const float* __restrict__ memg_b,
    const float* __restrict__ mem_scale, float* __restrict__ gated)
{
  const int b = blockIdx.x / H, h = blockIdx.x % H;
  const int tid = threadIdx.x;
  __shared__ float S[256][22];
  const int base = tid * 8;
  const size_t rb = (size_t)b * T;

  float M[21];
#pragma unroll
  for (int c = 0; c < 21; c++) M[c] = 0.f;
  float sloc[8];

  for (int j = 0; j < 8; j++) {
    const int t = base + j;
    const float4 w2 = *(const float4*)(proj + (rb + t) * PLDC + 48 + h * 4);
    float C[21];
#pragma unroll
    for (int c = 0; c < 21; c++) C[c] = 0.f;
    const int offs[4] = {1, 2, 4, 8};
#pragma unroll
    for (int oi = 0; oi < 4; oi++) {
      const int off = offs[oi];
      if (t >= off) {
        const float4 w1 = *(const float4*)(proj + (rb + t - off) * PLDC + 0 + h * 4);
        float L[6];
        ext_norm6(w1, w2, L);
        const float Jv[6] = { L[5], -L[4], L[3], L[2], -L[1], L[0] };
        int c = 0;
#pragma unroll
        for (int p = 0; p < 6; p++)
#pragma unroll
          for (int q = p; q < 6; q++) { C[c] += Jv[p] * Jv[q]; c++; }
      }
    }
    float R[6];
    {
      const float4 r1 = *(const float4*)(proj + (rb + t) * PLDC + 96 + h * 4);
      const float4 r2 = *(const float4*)(proj + (rb + t) * PLDC + 144 + h * 4);
      ext_norm6(r1, r2, R);
    }
    float qd = 0.f;
    {
      int c = 0;
#pragma unroll
      for (int p = 0; p < 6; p++) {
        qd += M[c] * R[p] * R[p]; c++;
#pragma unroll
        for (int q = p + 1; q < 6; q++) { qd += 2.f * M[c] * R[p] * R[q]; c++; }
      }
    }
    sloc[j] = qd;
#pragma unroll
    for (int cc = 0; cc < 21; cc++) M[cc] = DECAY_F * (M[cc] + C[cc]);
  }

#pragma unroll
  for (int c = 0; c < 21; c++) S[tid][c] = M[c];
  __syncthreads();
  if (tid < 21) {
    float pv = 0.f;
    const float d8 = 0.92274469442792013f;  // 0.99^8
    for (int i = 0; i < 256; i++) {
      float a = S[i][tid];
      S[i][tid] = pv;
      pv = d8 * pv + a;
    }
  }
  __syncthreads();
  float P[21];
#pragma unroll
  for (int c = 0; c < 21; c++) P[c] = S[tid][c];

  const float msc = mem_scale[h];
  const float gb = memg_b[h];
  float dj = 1.f;
  for (int j = 0; j < 8; j++) {
    const int t = base + j;
    float R[6];
    {
      const float4 r1 = *(const float4*)(proj + (rb + t) * PLDC + 96 + h * 4);
      const float4 r2 = *(const float4*)(proj + (rb + t) * PLDC + 144 + h * 4);
      ext_norm6(r1, r2, R);
    }
    float qd = 0.f;
    {
      int c = 0;
#pragma unroll
      for (int p = 0; p < 6; p++) {
        qd += P[c] * R[p] * R[p]; c++;
#pragma unroll
        for (int q = p + 1; q < 6; q++) { qd += 2.f * P[c] * R[p] * R[q]; c++; }
      }
    }
    const float score = (sloc[j] + dj * qd) * 0.25f;
    const float g1 = 1.f / (1.f + __expf(-score * msc));
    const float graw = proj[(rb + t) * PLDC + 192 + h] + gb;
    const float g2 = 1.f / (1.f + __expf(-graw));
    atomicAdd(&gated[rb + t], g1 * g2 * (1.f / 12.f));
    dj *= DECAY_F;
  }
}

// ---------------- z = o/rs + gated * memv  (bf16 out for final GEMM) ------
__global__ __launch_bounds__(256) void fuse_z(
    const float* __restrict__ o_acc, const float* __restrict__ rs_acc,
    const float* __restrict__ memv, const float* __restrict__ gated,
    ushort* __restrict__ zb)
{
  const int idx = blockIdx.x * 256 + threadIdx.x;
  const int row = idx / 96, c = (idx % 96) * 8;
  const int h = c >> 6;
  const float inv = 1.f / rs_acc[(size_t)row * H + h];
  const float g = gated[row];
  const float4 s0 = *(const float4*)(o_acc + (size_t)row * D + c);
  const float4 s1 = *(const float4*)(o_acc + (size_t)row * D + c + 4);
  const float4 m0 = *(const float4*)(memv + (size_t)row * D + c);
  const float4 m1 = *(const float4*)(memv + (size_t)row * D + c + 4);
  bf16x8 o;
  o[0] = (short)f2bf(s0.x * inv + g * m0.x); o[1] = (short)f2bf(s0.y * inv + g * m0.y);
  o[2] = (short)f2bf(s0.z * inv + g * m0.z); o[3] = (short)f2bf(s0.w * inv + g * m0.w);
  o[4] = (short)f2bf(s1.x * inv + g * m1.x); o[5] = (short)f2bf(s1.y * inv + g * m1.y);
  o[6] = (short)f2bf(s1.z * inv + g * m1.z); o[7] = (short)f2bf(s1.w * inv + g * m1.w);
  *(bf16x8*)(zb + (size_t)row * D + c) = o;
}

extern "C" void kernel_launch(void* const* d_in, const int* in_sizes, int n_in,
                              void* d_out, int out_size, void* d_ws, size_t ws_size,
                              hipStream_t stream)
{
  const float* x      = (const float*)d_in[0];
  const float* qkv_w  = (const float*)d_in[1];
  const float* qkv_b  = (const float*)d_in[2];
  const float* w1w    = (const float*)d_in[3];
  const float* w2w    = (const float*)d_in[4];
  const float* w1r    = (const float*)d_in[5];
  const float* w2r    = (const float*)d_in[6];
  const float* memv_w = (const float*)d_in[7];
  const float* memv_b = (const float*)d_in[8];
  const float* memg_w = (const float*)d_in[9];
  const float* memg_b = (const float*)d_in[10];
  const float* mem_scale = (const float*)d_in[11];
  const float* out_w  = (const float*)d_in[12];
  const float* out_b  = (const float*)d_in[13];
  float* out = (float*)d_out;

  float* ws    = (float*)d_ws;
  float* o_acc = ws;                              // [4096][768] f32
  float* memv  = o_acc + (size_t)NBT * D;         // [4096][768] f32
  float* proj  = memv + (size_t)NBT * D;          // [4096][204] f32
  float* gated = proj + (size_t)NBT * PLDC;       // [4096]
  float* rs_acc = gated + NBT;                    // [4096][12]
  ushort* Xb  = (ushort*)(rs_acc + (size_t)NBT * H);  // [4096][768] bf16
  ushort* Wb  = Xb + (size_t)NBT * D;             // [4096][768] bf16 (cast_all layout)
  ushort* Qb  = Wb + (size_t)NBT * D;             // [24][2048][64]
  ushort* Kb  = Qb + (size_t)24 * T * 64;
  ushort* Vtb = Kb + (size_t)24 * T * 64;         // [24][64][2048]
  ushort* zb  = Vtb + (size_t)24 * T * 64;        // [4096][768] bf16

  const ushort* W_out = Wb + (size_t)3328 * 768;

  dim3 blk(256);
  cast_all<<<dim3(3072), blk, 0, stream>>>(x, qkv_w, memv_w, out_w,
                                           w1w, w2w, w1r, w2r, memg_w, Xb);

  // merged qkv + memv + proj GEMM (N = 3328 incl. zero-pad)
  gemm_mfma<1><<<dim3(26, 32), blk, 0, stream>>>(Xb, Wb, qkv_b, nullptr, 0,
                                                 memv_b, memv, proj, Qb, Kb, Vtb);

  hipMemsetAsync(o_acc, 0, (size_t)NBT * D * sizeof(float), stream);
  hipMemsetAsync(rs_acc, 0, (size_t)NBT * H * sizeof(float), stream);
  hipMemsetAsync(gated, 0, NBT * sizeof(float), stream);

  attn_mfma<<<dim3(24 * 72), blk, 0, stream>>>(Qb, Kb, Vtb, o_acc, rs_acc);
  memscan<<<dim3(2 * H), blk, 0, stream>>>(proj, memg_b, mem_scale, gated);

  fuse_z<<<dim3(NBT * 96 / 256), blk, 0, stream>>>(o_acc, rs_acc, memv, gated, zb);
  gemm_mfma<0><<<dim3(6, 32), blk, 0, stream>>>(zb, W_out, out_b, out, 768,
                                                nullptr, nullptr, nullptr,
                                                nullptr, nullptr, nullptr);
}

// Round 5
// 159.387 us; speedup vs baseline: 11.2154x; 1.2880x over previous
//
#include <hip/hip_runtime.h>

#define H 12
#define T 2048
#define D 768
#define NBT 4096            // B*T
#define SCALE 0.125f
#define DECAY_F 0.99f
#define NCHK 72             // split-s chunk slots per bh
#define NBLK_ATTN (24 * NCHK)

typedef __attribute__((ext_vector_type(8))) short bf16x8;
typedef __attribute__((ext_vector_type(4))) float f32x4;
typedef __attribute__((ext_vector_type(16))) float f32x16;

static __device__ __forceinline__ ushort f2bf(float f) {
  union { float f; unsigned u; } v; v.f = f;
  unsigned r = (v.u + 0x7FFFu + ((v.u >> 16) & 1u)) >> 16;
  return (ushort)r;
}
static __device__ __forceinline__ float bf2f(ushort u) {
  union { unsigned u; float f; } v; v.u = ((unsigned)u) << 16;
  return v.f;
}

static __device__ __forceinline__ void gload16(const void* g, void* s) {
  __builtin_amdgcn_global_load_lds(
      (const __attribute__((address_space(1))) unsigned int*)g,
      (__attribute__((address_space(3))) unsigned int*)s, 16, 0, 0);
}

// ---------------- cast x + all weights to bf16 (flat segmented) ----------
// dst rows (768 wide): [x:4096 | qkv:2304 | memv:768 | w1w:48 | w2w:48 | w1r:48
//                       | w2r:48 | memg:12 | pad:52 | out:768]
__global__ __launch_bounds__(256) void cast_all(
    const float* __restrict__ x, const float* __restrict__ qkv_w,
    const float* __restrict__ memv_w, const float* __restrict__ out_w,
    const float* __restrict__ w1w, const float* __restrict__ w2w,
    const float* __restrict__ w1r, const float* __restrict__ w2r,
    const float* __restrict__ memg_w, ushort* __restrict__ dst)
{
  const size_t i8 = ((size_t)blockIdx.x * 256 + threadIdx.x) * 8;
  const float* src; size_t off;
  if      (i8 < 3145728) { src = x;      off = i8; }
  else if (i8 < 4915200) { src = qkv_w;  off = i8 - 3145728; }
  else if (i8 < 5505024) { src = memv_w; off = i8 - 4915200; }
  else if (i8 < 5541888) { src = w1w;    off = i8 - 5505024; }
  else if (i8 < 5578752) { src = w2w;    off = i8 - 5541888; }
  else if (i8 < 5615616) { src = w1r;    off = i8 - 5578752; }
  else if (i8 < 5652480) { src = w2r;    off = i8 - 5615616; }
  else if (i8 < 5661696) { src = memg_w; off = i8 - 5652480; }
  else if (i8 < 5701632) { *(uint4*)(dst + i8) = make_uint4(0, 0, 0, 0); return; }
  else                   { src = out_w;  off = i8 - 5701632; }
  const float4 a = *(const float4*)(src + off);
  const float4 b = *(const float4*)(src + off + 4);
  bf16x8 o;
  o[0] = (short)f2bf(a.x); o[1] = (short)f2bf(a.y);
  o[2] = (short)f2bf(a.z); o[3] = (short)f2bf(a.w);
  o[4] = (short)f2bf(b.x); o[5] = (short)f2bf(b.y);
  o[6] = (short)f2bf(b.z); o[7] = (short)f2bf(b.w);
  *(bf16x8*)(dst + i8) = o;
}

// ---------------- bf16 MFMA GEMM: C = A[M,768] @ W[N,768]^T ---------------
// 128x128 tile, BK=64, 4 waves (2x2), 4x4 16x16x32 fragments per wave.
// MODE 0: fp32 C + bias (out-GEMM)
// MODE 1: mega epilogue: col<2304 qkv->Qb/Kb/Vtb; <3072 memv f32; <3276 proj f32
template<int MODE>
__global__ __launch_bounds__(256) void gemm_mfma(
    const ushort* __restrict__ A, const ushort* __restrict__ W,
    const float* __restrict__ bias, float* __restrict__ C, int ldc,
    const float* __restrict__ memv_b, float* __restrict__ memvp,
    float* __restrict__ projp,
    ushort* __restrict__ Qb, ushort* __restrict__ Kb, ushort* __restrict__ Vtb)
{
  __shared__ ushort A_lds[128 * 64];
  __shared__ ushort B_lds[128 * 64];
  const int tid = threadIdx.x;
  const int w = tid >> 6, l = tid & 63;
  const int wm = w >> 1, wn = w & 1;
  const int bm = blockIdx.y * 128, bn = blockIdx.x * 128;
  const int l15 = l & 15, l4 = l >> 4;

  f32x4 acc[4][4];
#pragma unroll
  for (int i = 0; i < 4; i++)
#pragma unroll
    for (int j = 0; j < 4; j++) acc[i][j] = (f32x4){0.f, 0.f, 0.f, 0.f};

  const int srow = w * 32 + (l >> 3);
  const int scol = (l & 7) * 8;
  const ushort* Ag = A + (size_t)(bm + srow) * 768 + scol;
  const ushort* Wg = W + (size_t)(bn + srow) * 768 + scol;
  ushort* Asl = &A_lds[(w * 32) * 64];
  ushort* Bsl = &B_lds[(w * 32) * 64];

  for (int k0 = 0; k0 < 768; k0 += 64) {
#pragma unroll
    for (int i = 0; i < 4; i++) {
      gload16(Ag + k0 + i * 8 * 768, Asl + i * 8 * 64);
      gload16(Wg + k0 + i * 8 * 768, Bsl + i * 8 * 64);
    }
    __syncthreads();
#pragma unroll
    for (int ks = 0; ks < 2; ks++) {
      bf16x8 af[4], bfr[4];
#pragma unroll
      for (int i = 0; i < 4; i++) {
        af[i]  = *(const bf16x8*)&A_lds[(wm * 64 + i * 16 + l15) * 64 + ks * 32 + l4 * 8];
        bfr[i] = *(const bf16x8*)&B_lds[(wn * 64 + i * 16 + l15) * 64 + ks * 32 + l4 * 8];
      }
#pragma unroll
      for (int mi = 0; mi < 4; mi++)
#pragma unroll
        for (int ni = 0; ni < 4; ni++)
          acc[mi][ni] = __builtin_amdgcn_mfma_f32_16x16x32_bf16(af[mi], bfr[ni], acc[mi][ni], 0, 0, 0);
    }
    __syncthreads();
  }

  if (MODE == 0) {
#pragma unroll
    for (int mi = 0; mi < 4; mi++) {
      const int row0 = bm + wm * 64 + mi * 16 + l4 * 4;
#pragma unroll
      for (int ni = 0; ni < 4; ni++) {
        const int col = bn + wn * 64 + ni * 16 + l15;
        const float bv = bias[col];
#pragma unroll
        for (int r = 0; r < 4; r++)
          C[(size_t)(row0 + r) * ldc + col] = acc[mi][ni][r] + bv;
      }
    }
  } else {
#pragma unroll
    for (int mi = 0; mi < 4; mi++) {
      const int row0 = bm + wm * 64 + mi * 16 + l4 * 4;
      const int b = row0 >> 11, tl = row0 & (T - 1);
#pragma unroll
      for (int ni = 0; ni < 4; ni++) {
        const int col = bn + wn * 64 + ni * 16 + l15;
        if (col < 2304) {
          const float bv = bias[col];
          const int sec = col / 768, cm = col % 768;
          const int h = cm >> 6, d = cm & 63;
          if (sec < 2) {
            ushort* dst = sec ? Kb : Qb;
#pragma unroll
            for (int r = 0; r < 4; r++)
              dst[((size_t)(b * H + h) * T + tl + r) * 64 + d] = f2bf(acc[mi][ni][r] + bv);
          } else {
            uint2 u;
            u.x = (unsigned)f2bf(acc[mi][ni][0] + bv) | ((unsigned)f2bf(acc[mi][ni][1] + bv) << 16);
            u.y = (unsigned)f2bf(acc[mi][ni][2] + bv) | ((unsigned)f2bf(acc[mi][ni][3] + bv) << 16);
            *(uint2*)(Vtb + ((size_t)(b * H + h) * 64 + d) * T + tl) = u;
          }
        } else if (col < 3072) {
          const int c2 = col - 2304;
          const float bv = memv_b[c2];
#pragma unroll
          for (int r = 0; r < 4; r++)
            memvp[(size_t)(row0 + r) * 768 + c2] = acc[mi][ni][r] + bv;
        } else if (col < 3276) {
          const int c2 = col - 3072;
#pragma unroll
          for (int r = 0; r < 4; r++)
            projp[(size_t)(row0 + r) * 204 + c2] = acc[mi][ni][r];
        }
      }
    }
  }
}

// ---------------- bf16 MFMA flash attention, split-s, private partials ----
// grid: 24*72 blocks; per bh: 72 = sum over qb of ((qb>>1)+1) s-chunks.
// Each block: q-tile qb (128 rows, 4 waves x 32), s-chunk of <=4 64-tiles.
// Writes o_part[bid][128][64] bf16 and rs_part[bid][128] f32 (no atomics).
__global__ __launch_bounds__(256) void attn_mfma(
    const ushort* __restrict__ Qb, const ushort* __restrict__ Kb,
    const ushort* __restrict__ Vtb, ushort* __restrict__ o_part,
    float* __restrict__ rs_part)
{
  const int bh = blockIdx.x / NCHK;
  int ci = blockIdx.x % NCHK;
  int qb = 15;
#pragma unroll
  for (int q = 0; q < 16; q++) {
    const int cnt = (q >> 1) + 1;
    if (ci < cnt) { qb = q; break; }
    ci -= cnt;
  }
  const int t0 = qb * 128;
  const int it0 = ci * 4;
  const int it1 = min(it0 + 4, 2 * qb + 2);

  const int tid = threadIdx.x;
  const int w = tid >> 6;
  const int l = tid & 63;
  const int l31 = l & 31;
  const int lhi = l >> 5;

  __shared__ ushort K_lds[64][72];
  __shared__ ushort V_lds[64][72];
  __shared__ ushort P_lds[4][32][72];

  bf16x8 qf[4];
  {
    const ushort* qp = Qb + ((size_t)bh * T + t0 + w * 32 + l31) * 64 + 8 * lhi;
#pragma unroll
    for (int kf = 0; kf < 4; kf++) qf[kf] = *(const bf16x8*)(qp + kf * 16);
  }
  f32x16 o0, o1;
#pragma unroll
  for (int r = 0; r < 16; r++) { o0[r] = 0.f; o1[r] = 0.f; }
  float rs[16];
#pragma unroll
  for (int r = 0; r < 16; r++) rs[r] = 0.f;

  const int sr = tid >> 2;
  const int scg = (tid & 3) * 16;
  const ushort* ksrc = Kb + ((size_t)bh * T + sr) * 64 + scg;
  const ushort* vsrc = Vtb + ((size_t)bh * 64 + sr) * T + scg;
  const int qlo = t0 + w * 32;

  bf16x8 kp0, kp1, vp0, vp1;
  {
    const size_t s0 = (size_t)it0 * 64;
    kp0 = *(const bf16x8*)(ksrc + s0 * 64);
    kp1 = *(const bf16x8*)(ksrc + s0 * 64 + 8);
    vp0 = *(const bf16x8*)(vsrc + s0);
    vp1 = *(const bf16x8*)(vsrc + s0 + 8);
  }

  for (int it = it0; it < it1; ++it) {
    __syncthreads();
    *(bf16x8*)&K_lds[sr][scg] = kp0;
    *(bf16x8*)&K_lds[sr][scg + 8] = kp1;
    *(bf16x8*)&V_lds[sr][scg] = vp0;
    *(bf16x8*)&V_lds[sr][scg + 8] = vp1;
    __syncthreads();
    if (it + 1 < it1) {
      const size_t s0n = (size_t)(it + 1) * 64;
      kp0 = *(const bf16x8*)(ksrc + s0n * 64);
      kp1 = *(const bf16x8*)(ksrc + s0n * 64 + 8);
      vp0 = *(const bf16x8*)(vsrc + s0n);
      vp1 = *(const bf16x8*)(vsrc + s0n + 8);
    }
    const int s0 = it * 64;
    if (s0 > qlo + 31) continue;      // fully masked for this wave

    f32x16 sA, sB;
#pragma unroll
    for (int r = 0; r < 16; r++) { sA[r] = 0.f; sB[r] = 0.f; }
#pragma unroll
    for (int kf = 0; kf < 4; kf++) {
      const bf16x8 ka = *(const bf16x8*)&K_lds[l31][kf * 16 + 8 * lhi];
      const bf16x8 kb2 = *(const bf16x8*)&K_lds[32 + l31][kf * 16 + 8 * lhi];
      sA = __builtin_amdgcn_mfma_f32_32x32x16_bf16(qf[kf], ka, sA, 0, 0, 0);
      sB = __builtin_amdgcn_mfma_f32_32x32x16_bf16(qf[kf], kb2, sB, 0, 0, 0);
    }
    const bool nomask = (s0 + 63 <= qlo);
#pragma unroll
    for (int r = 0; r < 16; r++) {
      const int qrow = (r & 3) + 8 * (r >> 2) + 4 * lhi;
      const int qg = qlo + qrow;
      float pa = __expf(sA[r] * SCALE);
      float pb = __expf(sB[r] * SCALE);
      if (!nomask) {
        if (s0 + l31 > qg) pa = 0.f;
        if (s0 + 32 + l31 > qg) pb = 0.f;
      }
      rs[r] += pa + pb;
      P_lds[w][qrow][l31] = f2bf(pa);
      P_lds[w][qrow][32 + l31] = f2bf(pb);
    }
#pragma unroll
    for (int ks = 0; ks < 4; ks++) {
      const bf16x8 pf = *(const bf16x8*)&P_lds[w][l31][ks * 16 + 8 * lhi];
      const bf16x8 va = *(const bf16x8*)&V_lds[l31][ks * 16 + 8 * lhi];
      const bf16x8 vb = *(const bf16x8*)&V_lds[32 + l31][ks * 16 + 8 * lhi];
      o0 = __builtin_amdgcn_mfma_f32_32x32x16_bf16(pf, va, o0, 0, 0, 0);
      o1 = __builtin_amdgcn_mfma_f32_32x32x16_bf16(pf, vb, o1, 0, 0, 0);
    }
  }

#pragma unroll
  for (int r = 0; r < 16; r++) {
    float v = rs[r];
    v += __shfl_xor(v, 1); v += __shfl_xor(v, 2); v += __shfl_xor(v, 4);
    v += __shfl_xor(v, 8); v += __shfl_xor(v, 16);
    rs[r] = v;
  }
  ushort* ob = o_part + (size_t)blockIdx.x * 128 * 64;
  float* rsb = rs_part + (size_t)blockIdx.x * 128;
#pragma unroll
  for (int r = 0; r < 16; r++) {
    const int brow = w * 32 + (r & 3) + 8 * (r >> 2) + 4 * lhi;
    ob[brow * 64 + l31] = f2bf(o0[r]);
    ob[brow * 64 + 32 + l31] = f2bf(o1[r]);
    if (l31 == 0) rsb[brow] = rs[r];
  }
}

// ---------------- Plucker memory: chunked decay scan ----------------
__device__ __forceinline__ void ext_norm6(const float4 a, const float4 b, float* L)
{
  L[0] = a.x * b.y - a.y * b.x;
  L[1] = a.x * b.z - a.z * b.x;
  L[2] = a.x * b.w - a.w * b.x;
  L[3] = a.y * b.z - a.z * b.y;
  L[4] = a.y * b.w - a.w * b.y;
  L[5] = a.z * b.w - a.w * b.z;
  float n2 = L[0]*L[0] + L[1]*L[1] + L[2]*L[2] + L[3]*L[3] + L[4]*L[4] + L[5]*L[5];
  float n = fmaxf(sqrtf(n2), 1e-12f);
  float inv = 1.f / n;
#pragma unroll
  for (int i = 0; i < 6; i++) L[i] *= inv;
}

#define PLDC 204
// proj row: [w1w:0..47 | w2w:48..95 | w1r:96..143 | w2r:144..191 | memg:192..203]
__global__ __launch_bounds__(256) void memscan(
    const float* __restrict__ proj, const float* __restrict__ memg_b,
    const float* __restrict__ mem_scale, float* __restrict__ gated)
{
  const int b = blockIdx.x / H, h = blockIdx.x % H;
  const int tid = threadIdx.x;
  __shared__ float S[256][22];
  const int base = tid * 8;
  const size_t rb = (size_t)b * T;

  float M[21];
#pragma unroll
  for (int c = 0; c < 21; c++) M[c] = 0.f;
  float sloc[8];

  for (int j = 0; j < 8; j++) {
    const int t = base + j;
    const float4 w2 = *(const float4*)(proj + (rb + t) * PLDC + 48 + h * 4);
    float C[21];
#pragma unroll
    for (int c = 0; c < 21; c++) C[c] = 0.f;
    const int offs[4] = {1, 2, 4, 8};
#pragma unroll
    for (int oi = 0; oi < 4; oi++) {
      const int off = offs[oi];
      if (t >= off) {
        const float4 w1 = *(const float4*)(proj + (rb + t - off) * PLDC + 0 + h * 4);
        float L[6];
        ext_norm6(w1, w2, L);
        const float Jv[6] = { L[5], -L[4], L[3], L[2], -L[1], L[0] };
        int c = 0;
#pragma unroll
        for (int p = 0; p < 6; p++)
#pragma unroll
          for (int q = p; q < 6; q++) { C[c] += Jv[p] * Jv[q]; c++; }
      }
    }
    float R[6];
    {
      const float4 r1 = *(const float4*)(proj + (rb + t) * PLDC + 96 + h * 4);
      const float4 r2 = *(const float4*)(proj + (rb + t) * PLDC + 144 + h * 4);
      ext_norm6(r1, r2, R);
    }
    float qd = 0.f;
    {
      int c = 0;
#pragma unroll
      for (int p = 0; p < 6; p++) {
        qd += M[c] * R[p] * R[p]; c++;
#pragma unroll
        for (int q = p + 1; q < 6; q++) { qd += 2.f * M[c] * R[p] * R[q]; c++; }
      }
    }
    sloc[j] = qd;
#pragma unroll
    for (int cc = 0; cc < 21; cc++) M[cc] = DECAY_F * (M[cc] + C[cc]);
  }

#pragma unroll
  for (int c = 0; c < 21; c++) S[tid][c] = M[c];
  __syncthreads();
  if (tid < 21) {
    float pv = 0.f;
    const float d8 = 0.92274469442792013f;  // 0.99^8
    for (int i = 0; i < 256; i++) {
      float a = S[i][tid];
      S[i][tid] = pv;
      pv = d8 * pv + a;
    }
  }
  __syncthreads();
  float P[21];
#pragma unroll
  for (int c = 0; c < 21; c++) P[c] = S[tid][c];

  const float msc = mem_scale[h];
  const float gb = memg_b[h];
  float dj = 1.f;
  for (int j = 0; j < 8; j++) {
    const int t = base + j;
    float R[6];
    {
      const float4 r1 = *(const float4*)(proj + (rb + t) * PLDC + 96 + h * 4);
      const float4 r2 = *(const float4*)(proj + (rb + t) * PLDC + 144 + h * 4);
      ext_norm6(r1, r2, R);
    }
    float qd = 0.f;
    {
      int c = 0;
#pragma unroll
      for (int p = 0; p < 6; p++) {
        qd += P[c] * R[p] * R[p]; c++;
#pragma unroll
        for (int q = p + 1; q < 6; q++) { qd += 2.f * P[c] * R[p] * R[q]; c++; }
      }
    }
    const float score = (sloc[j] + dj * qd) * 0.25f;
    const float g1 = 1.f / (1.f + __expf(-score * msc));
    const float graw = proj[(rb + t) * PLDC + 192 + h] + gb;
    const float g2 = 1.f / (1.f + __expf(-graw));
    atomicAdd(&gated[rb + t], g1 * g2 * (1.f / 12.f));
    dj *= DECAY_F;
  }
}

// ------- reduce partials + normalize + gate fuse -> bf16 z ---------------
__global__ __launch_bounds__(256) void reduce_fuse(
    const ushort* __restrict__ o_part, const float* __restrict__ rs_part,
    const float* __restrict__ memv, const float* __restrict__ gated,
    ushort* __restrict__ zb)
{
  const int idx = blockIdx.x * 256 + threadIdx.x;
  const int row = idx / 96, c = (idx % 96) * 8;
  const int h = c >> 6, d0 = c & 63;
  const int b = row >> 11, tl = row & (T - 1);
  const int qb = tl >> 7, rloc = tl & 127;
  const int m = qb >> 1;
  const int cnt = m + 1;
  const int base = m * (m + 1) + (qb & 1) * (m + 1);
  const size_t bid0 = (size_t)(b * H + h) * NCHK + base;

  float o[8] = {0.f, 0.f, 0.f, 0.f, 0.f, 0.f, 0.f, 0.f};
  float rsum = 0.f;
  for (int ci = 0; ci < cnt; ci++) {
    const bf16x8 pv = *(const bf16x8*)(o_part + ((bid0 + ci) * 128 + rloc) * 64 + d0);
#pragma unroll
    for (int j = 0; j < 8; j++) o[j] += bf2f((ushort)pv[j]);
    rsum += rs_part[(bid0 + ci) * 128 + rloc];
  }
  const float inv = 1.f / rsum;
  const float g = gated[row];
  const float4 m0 = *(const float4*)(memv + (size_t)row * D + c);
  const float4 m1 = *(const float4*)(memv + (size_t)row * D + c + 4);
  bf16x8 z;
  z[0] = (short)f2bf(o[0] * inv + g * m0.x); z[1] = (short)f2bf(o[1] * inv + g * m0.y);
  z[2] = (short)f2bf(o[2] * inv + g * m0.z); z[3] = (short)f2bf(o[3] * inv + g * m0.w);
  z[4] = (short)f2bf(o[4] * inv + g * m1.x); z[5] = (short)f2bf(o[5] * inv + g * m1.y);
  z[6] = (short)f2bf(o[6] * inv + g * m1.z); z[7] = (short)f2bf(o[7] * inv + g * m1.w);
  *(bf16x8*)(zb + (size_t)row * D + c) = z;
}

extern "C" void kernel_launch(void* const* d_in, const int* in_sizes, int n_in,
                              void* d_out, int out_size, void* d_ws, size_t ws_size,
                              hipStream_t stream)
{
  const float* x      = (const float*)d_in[0];
  const float* qkv_w  = (const float*)d_in[1];
  const float* qkv_b  = (const float*)d_in[2];
  const float* w1w    = (const float*)d_in[3];
  const float* w2w    = (const float*)d_in[4];
  const float* w1r    = (const float*)d_in[5];
  const float* w2r    = (const float*)d_in[6];
  const float* memv_w = (const float*)d_in[7];
  const float* memv_b = (const float*)d_in[8];
  const float* memg_w = (const float*)d_in[9];
  const float* memg_b = (const float*)d_in[10];
  const float* mem_scale = (const float*)d_in[11];
  const float* out_w  = (const float*)d_in[12];
  const float* out_b  = (const float*)d_in[13];
  float* out = (float*)d_out;

  float* ws    = (float*)d_ws;
  float* memv  = ws;                              // [4096][768] f32
  float* proj  = memv + (size_t)NBT * D;          // [4096][204] f32
  float* gated = proj + (size_t)NBT * PLDC;       // [4096]
  float* rs_part = gated + NBT;                   // [1728][128] f32
  ushort* Xb  = (ushort*)(rs_part + (size_t)NBLK_ATTN * 128);  // [4096][768]
  ushort* Wb  = Xb + (size_t)NBT * D;             // cast_all weight rows
  ushort* Qb  = Wb + (size_t)NBT * D;             // [24][2048][64]
  ushort* Kb  = Qb + (size_t)24 * T * 64;
  ushort* Vtb = Kb + (size_t)24 * T * 64;         // [24][64][2048]
  ushort* zb  = Vtb + (size_t)24 * T * 64;        // [4096][768]
  ushort* o_part = zb + (size_t)NBT * D;          // [1728][128][64] bf16

  const ushort* W_out = Wb + (size_t)3328 * 768;

  dim3 blk(256);
  cast_all<<<dim3(3072), blk, 0, stream>>>(x, qkv_w, memv_w, out_w,
                                           w1w, w2w, w1r, w2r, memg_w, Xb);

  // merged qkv + memv + proj GEMM (N = 3328 incl. zero-pad)
  gemm_mfma<1><<<dim3(26, 32), blk, 0, stream>>>(Xb, Wb, qkv_b, nullptr, 0,
                                                 memv_b, memv, proj, Qb, Kb, Vtb);

  hipMemsetAsync(gated, 0, NBT * sizeof(float), stream);

  attn_mfma<<<dim3(NBLK_ATTN), blk, 0, stream>>>(Qb, Kb, Vtb, o_part, rs_part);
  memscan<<<dim3(2 * H), blk, 0, stream>>>(proj, memg_b, mem_scale, gated);

  reduce_fuse<<<dim3(NBT * 96 / 256), blk, 0, stream>>>(o_part, rs_part, memv,
                                                        gated, zb);
  gemm_mfma<0><<<dim3(6, 32), blk, 0, stream>>>(zb, W_out, out_b, out, 768,
                                                nullptr, nullptr, nullptr,
                                                nullptr, nullptr, nullptr);
}

// Round 6
// 145.782 us; speedup vs baseline: 12.2622x; 1.0933x over previous
//
#include <hip/hip_runtime.h>

#define H 12
#define T 2048
#define D 768
#define NBT 4096            // B*T
#define SCALE 0.125f
#define DECAY_F 0.99f
#define NCHK 72             // split-s chunk slots per bh
#define NBLK_ATTN (24 * NCHK)

typedef __attribute__((ext_vector_type(8))) short bf16x8;
typedef __attribute__((ext_vector_type(4))) float f32x4;
typedef __attribute__((ext_vector_type(16))) float f32x16;

static __device__ __forceinline__ ushort f2bf(float f) {
  union { float f; unsigned u; } v; v.f = f;
  unsigned r = (v.u + 0x7FFFu + ((v.u >> 16) & 1u)) >> 16;
  return (ushort)r;
}
static __device__ __forceinline__ float bf2f(ushort u) {
  union { unsigned u; float f; } v; v.u = ((unsigned)u) << 16;
  return v.f;
}

static __device__ __forceinline__ void gload16(const void* g, void* s) {
  __builtin_amdgcn_global_load_lds(
      (const __attribute__((address_space(1))) unsigned int*)g,
      (__attribute__((address_space(3))) unsigned int*)s, 16, 0, 0);
}

// ---------------- cast x + all weights to bf16 (flat segmented) ----------
// dst rows (768 wide): [x:4096 | qkv:2304 | memv:768 | w1w:48 | w2w:48 | w1r:48
//                       | w2r:48 | memg:12 | pad:52 | out:768]
__global__ __launch_bounds__(256) void cast_all(
    const float* __restrict__ x, const float* __restrict__ qkv_w,
    const float* __restrict__ memv_w, const float* __restrict__ out_w,
    const float* __restrict__ w1w, const float* __restrict__ w2w,
    const float* __restrict__ w1r, const float* __restrict__ w2r,
    const float* __restrict__ memg_w, ushort* __restrict__ dst)
{
  const size_t i8 = ((size_t)blockIdx.x * 256 + threadIdx.x) * 8;
  const float* src; size_t off;
  if      (i8 < 3145728) { src = x;      off = i8; }
  else if (i8 < 4915200) { src = qkv_w;  off = i8 - 3145728; }
  else if (i8 < 5505024) { src = memv_w; off = i8 - 4915200; }
  else if (i8 < 5541888) { src = w1w;    off = i8 - 5505024; }
  else if (i8 < 5578752) { src = w2w;    off = i8 - 5541888; }
  else if (i8 < 5615616) { src = w1r;    off = i8 - 5578752; }
  else if (i8 < 5652480) { src = w2r;    off = i8 - 5615616; }
  else if (i8 < 5661696) { src = memg_w; off = i8 - 5652480; }
  else if (i8 < 5701632) { *(uint4*)(dst + i8) = make_uint4(0, 0, 0, 0); return; }
  else                   { src = out_w;  off = i8 - 5701632; }
  const float4 a = *(const float4*)(src + off);
  const float4 b = *(const float4*)(src + off + 4);
  bf16x8 o;
  o[0] = (short)f2bf(a.x); o[1] = (short)f2bf(a.y);
  o[2] = (short)f2bf(a.z); o[3] = (short)f2bf(a.w);
  o[4] = (short)f2bf(b.x); o[5] = (short)f2bf(b.y);
  o[6] = (short)f2bf(b.z); o[7] = (short)f2bf(b.w);
  *(bf16x8*)(dst + i8) = o;
}

// ============ 8-phase 256x256 MFMA GEMM (mega epilogue) ===================
// C = A[4096,768] @ W[3328,768]^T. 512 thr = 8 waves (2M x 4N); BK=64;
// LDS 128KB: [slot(2)][A 256x64 | B 256x64] bf16, XOR-swizzled chunks.
// Per K-tile: 4 phases {stage half-tile of tile t+1 -> slot^1 | ds_read
// quadrant | 16 MFMA setprio-wrapped | s_barrier}; counted vmcnt(2) at p0.
__global__ __launch_bounds__(512, 2) void gemm8_mega(
    const ushort* __restrict__ A, const ushort* __restrict__ W,
    const float* __restrict__ qkv_b, const float* __restrict__ memv_b,
    ushort* __restrict__ memvp, float* __restrict__ projp,
    ushort* __restrict__ Qb, ushort* __restrict__ Kb, ushort* __restrict__ Vtb)
{
  __shared__ ushort lds[65536];   // 128 KiB
  const int tid = threadIdx.x;
  const int w = tid >> 6, l = tid & 63;
  const int wm = w >> 2, wn = w & 3;
  const int l15 = l & 15, l4 = l >> 4;

  // XCD-aware swizzle over 208 blocks (208 % 8 == 0 -> simple form valid)
  int bid = blockIdx.x;
  bid = (bid & 7) * 26 + (bid >> 3);
  const int bx = bid % 13, by = bid / 13;
  const int bm = by * 256, bn = bx * 256;

  f32x4 acc[8][4];
#pragma unroll
  for (int i = 0; i < 8; i++)
#pragma unroll
    for (int j = 0; j < 4; j++) acc[i][j] = (f32x4){0.f, 0.f, 0.f, 0.f};

  // stage one half-tile (isB, half h) of k-tile kt into slot s.
  // LDS dest linear by lane; global source chunk pre-swizzled (c ^= r&7).
  auto stage = [&](int s, int isB, int h, int kt) {
    const ushort* src = (isB ? W + (size_t)bn * 768 : A + (size_t)bm * 768);
#pragma unroll
    for (int j = 0; j < 2; j++) {
      const int chunk = j * 512 + tid;
      const int r = chunk >> 3, c = chunk & 7;
      const int csrc = c ^ (r & 7);
      gload16(src + (size_t)(h * 128 + r) * 768 + kt * 64 + csrc * 8,
              (char*)lds + s * 65536 + isB * 32768 + h * 16384
                         + (size_t)(j * 512 + w * 64) * 16);
    }
  };
  auto rdA = [&](int s, int mi, int ks) -> bf16x8 {
    const int row = wm * 128 + mi * 16 + l15;
    const int ch = (ks * 4 + l4) ^ (l15 & 7);
    return *(const bf16x8*)((const char*)lds + s * 65536 + row * 128 + ch * 16);
  };
  auto rdB = [&](int s, int ni, int ks) -> bf16x8 {
    const int row = wn * 64 + ni * 16 + l15;
    const int ch = (ks * 4 + l4) ^ (l15 & 7);
    return *(const bf16x8*)((const char*)lds + s * 65536 + 32768 + row * 128 + ch * 16);
  };

  // prologue: stage k-tile 0 into slot 0 (8 loads/thread)
  stage(0, 1, 0, 0); stage(0, 1, 1, 0); stage(0, 0, 0, 0); stage(0, 0, 1, 0);

#define MFMA_QUAD(mb, ks)                                                      \
  {                                                                            \
    __builtin_amdgcn_s_setprio(1);                                             \
    _Pragma("unroll")                                                          \
    for (int mi = 0; mi < 4; mi++) {                                           \
      const bf16x8 av = rdA(s, (mb) + mi, (ks));                               \
      acc[(mb)+mi][0] = __builtin_amdgcn_mfma_f32_16x16x32_bf16(av, bq0, acc[(mb)+mi][0], 0, 0, 0); \
      acc[(mb)+mi][1] = __builtin_amdgcn_mfma_f32_16x16x32_bf16(av, bq1, acc[(mb)+mi][1], 0, 0, 0); \
      acc[(mb)+mi][2] = __builtin_amdgcn_mfma_f32_16x16x32_bf16(av, bq2, acc[(mb)+mi][2], 0, 0, 0); \
      acc[(mb)+mi][3] = __builtin_amdgcn_mfma_f32_16x16x32_bf16(av, bq3, acc[(mb)+mi][3], 0, 0, 0); \
    }                                                                          \
    __builtin_amdgcn_s_setprio(0);                                             \
  }

  for (int t = 0; t < 12; t++) {
    const int s = t & 1, sn = s ^ 1;
    const int ktn = (t + 1) % 12;
    bf16x8 bq0, bq1, bq2, bq3;
    // ---- phase 0: vmcnt(2) waits the 8 loads of tile t; 2 new in flight ---
    stage(sn, 1, 0, ktn);
    asm volatile("s_waitcnt vmcnt(2)" ::: "memory");
    __builtin_amdgcn_s_barrier();
    __builtin_amdgcn_sched_barrier(0);
    bq0 = rdB(s, 0, 0); bq1 = rdB(s, 1, 0); bq2 = rdB(s, 2, 0); bq3 = rdB(s, 3, 0);
    MFMA_QUAD(0, 0);
    __builtin_amdgcn_s_barrier();
    // ---- phase 1 ----
    stage(sn, 1, 1, ktn);
    MFMA_QUAD(4, 0);
    __builtin_amdgcn_s_barrier();
    // ---- phase 2 ----
    stage(sn, 0, 0, ktn);
    bq0 = rdB(s, 0, 1); bq1 = rdB(s, 1, 1); bq2 = rdB(s, 2, 1); bq3 = rdB(s, 3, 1);
    MFMA_QUAD(0, 1);
    __builtin_amdgcn_s_barrier();
    // ---- phase 3 ----
    stage(sn, 0, 1, ktn);
    MFMA_QUAD(4, 1);
    __builtin_amdgcn_s_barrier();
  }

  // ---- mega epilogue: route columns ----
#pragma unroll
  for (int mi = 0; mi < 8; mi++) {
    const int row0 = bm + wm * 128 + mi * 16 + l4 * 4;
    const int b = row0 >> 11, tl = row0 & (T - 1);
#pragma unroll
    for (int ni = 0; ni < 4; ni++) {
      const int col = bn + wn * 64 + ni * 16 + l15;
      const f32x4 a4 = acc[mi][ni];
      if (col < 2304) {
        const float bv = qkv_b[col];
        const int sec = col / 768, cm = col % 768;
        const int h = cm >> 6, d = cm & 63;
        if (sec < 2) {
          ushort* dst = sec ? Kb : Qb;
#pragma unroll
          for (int r = 0; r < 4; r++)
            dst[((size_t)(b * H + h) * T + tl + r) * 64 + d] = f2bf(a4[r] + bv);
        } else {
          uint2 u;
          u.x = (unsigned)f2bf(a4[0] + bv) | ((unsigned)f2bf(a4[1] + bv) << 16);
          u.y = (unsigned)f2bf(a4[2] + bv) | ((unsigned)f2bf(a4[3] + bv) << 16);
          *(uint2*)(Vtb + ((size_t)(b * H + h) * 64 + d) * T + tl) = u;
        }
      } else if (col < 3072) {
        const int c2 = col - 2304;
        const float bv = memv_b[c2];
#pragma unroll
        for (int r = 0; r < 4; r++)
          memvp[(size_t)(row0 + r) * 768 + c2] = f2bf(a4[r] + bv);
      } else if (col < 3276) {
        const int c2 = col - 3072;
#pragma unroll
        for (int r = 0; r < 4; r++)
          projp[(size_t)(row0 + r) * 204 + c2] = a4[r];
      }
    }
  }
}

// ---------------- 128x128 MFMA GEMM (fp32 C + bias) — out-projection ------
__global__ __launch_bounds__(256) void gemm_mfma128(
    const ushort* __restrict__ A, const ushort* __restrict__ W,
    const float* __restrict__ bias, float* __restrict__ C, int ldc)
{
  __shared__ ushort A_lds[128 * 64];
  __shared__ ushort B_lds[128 * 64];
  const int tid = threadIdx.x;
  const int w = tid >> 6, l = tid & 63;
  const int wm = w >> 1, wn = w & 1;
  const int bm = blockIdx.y * 128, bn = blockIdx.x * 128;
  const int l15 = l & 15, l4 = l >> 4;

  f32x4 acc[4][4];
#pragma unroll
  for (int i = 0; i < 4; i++)
#pragma unroll
    for (int j = 0; j < 4; j++) acc[i][j] = (f32x4){0.f, 0.f, 0.f, 0.f};

  const int srow = w * 32 + (l >> 3);
  const int scol = (l & 7) * 8;
  const ushort* Ag = A + (size_t)(bm + srow) * 768 + scol;
  const ushort* Wg = W + (size_t)(bn + srow) * 768 + scol;
  ushort* Asl = &A_lds[(w * 32) * 64];
  ushort* Bsl = &B_lds[(w * 32) * 64];

  for (int k0 = 0; k0 < 768; k0 += 64) {
#pragma unroll
    for (int i = 0; i < 4; i++) {
      gload16(Ag + k0 + i * 8 * 768, Asl + i * 8 * 64);
      gload16(Wg + k0 + i * 8 * 768, Bsl + i * 8 * 64);
    }
    __syncthreads();
#pragma unroll
    for (int ks = 0; ks < 2; ks++) {
      bf16x8 af[4], bfr[4];
#pragma unroll
      for (int i = 0; i < 4; i++) {
        af[i]  = *(const bf16x8*)&A_lds[(wm * 64 + i * 16 + l15) * 64 + ks * 32 + l4 * 8];
        bfr[i] = *(const bf16x8*)&B_lds[(wn * 64 + i * 16 + l15) * 64 + ks * 32 + l4 * 8];
      }
#pragma unroll
      for (int mi = 0; mi < 4; mi++)
#pragma unroll
        for (int ni = 0; ni < 4; ni++)
          acc[mi][ni] = __builtin_amdgcn_mfma_f32_16x16x32_bf16(af[mi], bfr[ni], acc[mi][ni], 0, 0, 0);
    }
    __syncthreads();
  }
#pragma unroll
  for (int mi = 0; mi < 4; mi++) {
    const int row0 = bm + wm * 64 + mi * 16 + l4 * 4;
#pragma unroll
    for (int ni = 0; ni < 4; ni++) {
      const int col = bn + wn * 64 + ni * 16 + l15;
      const float bv = bias[col];
#pragma unroll
      for (int r = 0; r < 4; r++)
        C[(size_t)(row0 + r) * ldc + col] = acc[mi][ni][r] + bv;
    }
  }
}

// ---------------- bf16 MFMA flash attention, split-s, private partials ----
__global__ __launch_bounds__(256) void attn_mfma(
    const ushort* __restrict__ Qb, const ushort* __restrict__ Kb,
    const ushort* __restrict__ Vtb, ushort* __restrict__ o_part,
    float* __restrict__ rs_part)
{
  const int bh = blockIdx.x / NCHK;
  int ci = blockIdx.x % NCHK;
  int qb = 15;
#pragma unroll
  for (int q = 0; q < 16; q++) {
    const int cnt = (q >> 1) + 1;
    if (ci < cnt) { qb = q; break; }
    ci -= cnt;
  }
  const int t0 = qb * 128;
  const int it0 = ci * 4;
  const int it1 = min(it0 + 4, 2 * qb + 2);

  const int tid = threadIdx.x;
  const int w = tid >> 6;
  const int l = tid & 63;
  const int l31 = l & 31;
  const int lhi = l >> 5;

  __shared__ ushort K_lds[64][72];
  __shared__ ushort V_lds[64][72];
  __shared__ ushort P_lds[4][32][72];

  bf16x8 qf[4];
  {
    const ushort* qp = Qb + ((size_t)bh * T + t0 + w * 32 + l31) * 64 + 8 * lhi;
#pragma unroll
    for (int kf = 0; kf < 4; kf++) qf[kf] = *(const bf16x8*)(qp + kf * 16);
  }
  f32x16 o0, o1;
#pragma unroll
  for (int r = 0; r < 16; r++) { o0[r] = 0.f; o1[r] = 0.f; }
  float rs[16];
#pragma unroll
  for (int r = 0; r < 16; r++) rs[r] = 0.f;

  const int sr = tid >> 2;
  const int scg = (tid & 3) * 16;
  const ushort* ksrc = Kb + ((size_t)bh * T + sr) * 64 + scg;
  const ushort* vsrc = Vtb + ((size_t)bh * 64 + sr) * T + scg;
  const int qlo = t0 + w * 32;

  bf16x8 kp0, kp1, vp0, vp1;
  {
    const size_t s0 = (size_t)it0 * 64;
    kp0 = *(const bf16x8*)(ksrc + s0 * 64);
    kp1 = *(const bf16x8*)(ksrc + s0 * 64 + 8);
    vp0 = *(const bf16x8*)(vsrc + s0);
    vp1 = *(const bf16x8*)(vsrc + s0 + 8);
  }

  for (int it = it0; it < it1; ++it) {
    __syncthreads();
    *(bf16x8*)&K_lds[sr][scg] = kp0;
    *(bf16x8*)&K_lds[sr][scg + 8] = kp1;
    *(bf16x8*)&V_lds[sr][scg] = vp0;
    *(bf16x8*)&V_lds[sr][scg + 8] = vp1;
    __syncthreads();
    if (it + 1 < it1) {
      const size_t s0n = (size_t)(it + 1) * 64;
      kp0 = *(const bf16x8*)(ksrc + s0n * 64);
      kp1 = *(const bf16x8*)(ksrc + s0n * 64 + 8);
      vp0 = *(const bf16x8*)(vsrc + s0n);
      vp1 = *(const bf16x8*)(vsrc + s0n + 8);
    }
    const int s0 = it * 64;
    if (s0 > qlo + 31) continue;      // fully masked for this wave

    f32x16 sA, sB;
#pragma unroll
    for (int r = 0; r < 16; r++) { sA[r] = 0.f; sB[r] = 0.f; }
#pragma unroll
    for (int kf = 0; kf < 4; kf++) {
      const bf16x8 ka = *(const bf16x8*)&K_lds[l31][kf * 16 + 8 * lhi];
      const bf16x8 kb2 = *(const bf16x8*)&K_lds[32 + l31][kf * 16 + 8 * lhi];
      sA = __builtin_amdgcn_mfma_f32_32x32x16_bf16(qf[kf], ka, sA, 0, 0, 0);
      sB = __builtin_amdgcn_mfma_f32_32x32x16_bf16(qf[kf], kb2, sB, 0, 0, 0);
    }
    const bool nomask = (s0 + 63 <= qlo);
#pragma unroll
    for (int r = 0; r < 16; r++) {
      const int qrow = (r & 3) + 8 * (r >> 2) + 4 * lhi;
      const int qg = qlo + qrow;
      float pa = __expf(sA[r] * SCALE);
      float pb = __expf(sB[r] * SCALE);
      if (!nomask) {
        if (s0 + l31 > qg) pa = 0.f;
        if (s0 + 32 + l31 > qg) pb = 0.f;
      }
      rs[r] += pa + pb;
      P_lds[w][qrow][l31] = f2bf(pa);
      P_lds[w][qrow][32 + l31] = f2bf(pb);
    }
#pragma unroll
    for (int ks = 0; ks < 4; ks++) {
      const bf16x8 pf = *(const bf16x8*)&P_lds[w][l31][ks * 16 + 8 * lhi];
      const bf16x8 va = *(const bf16x8*)&V_lds[l31][ks * 16 + 8 * lhi];
      const bf16x8 vb = *(const bf16x8*)&V_lds[32 + l31][ks * 16 + 8 * lhi];
      o0 = __builtin_amdgcn_mfma_f32_32x32x16_bf16(pf, va, o0, 0, 0, 0);
      o1 = __builtin_amdgcn_mfma_f32_32x32x16_bf16(pf, vb, o1, 0, 0, 0);
    }
  }

#pragma unroll
  for (int r = 0; r < 16; r++) {
    float v = rs[r];
    v += __shfl_xor(v, 1); v += __shfl_xor(v, 2); v += __shfl_xor(v, 4);
    v += __shfl_xor(v, 8); v += __shfl_xor(v, 16);
    rs[r] = v;
  }
  ushort* ob = o_part + (size_t)blockIdx.x * 128 * 64;
  float* rsb = rs_part + (size_t)blockIdx.x * 128;
#pragma unroll
  for (int r = 0; r < 16; r++) {
    const int brow = w * 32 + (r & 3) + 8 * (r >> 2) + 4 * lhi;
    ob[brow * 64 + l31] = f2bf(o0[r]);
    ob[brow * 64 + 32 + l31] = f2bf(o1[r]);
    if (l31 == 0) rsb[brow] = rs[r];
  }
}

// ---------------- Plucker memory: chunked decay scan ----------------
__device__ __forceinline__ void ext_norm6(const float4 a, const float4 b, float* L)
{
  L[0] = a.x * b.y - a.y * b.x;
  L[1] = a.x * b.z - a.z * b.x;
  L[2] = a.x * b.w - a.w * b.x;
  L[3] = a.y * b.z - a.z * b.y;
  L[4] = a.y * b.w - a.w * b.y;
  L[5] = a.z * b.w - a.w * b.z;
  float n2 = L[0]*L[0] + L[1]*L[1] + L[2]*L[2] + L[3]*L[3] + L[4]*L[4] + L[5]*L[5];
  float n = fmaxf(sqrtf(n2), 1e-12f);
  float inv = 1.f / n;
#pragma unroll
  for (int i = 0; i < 6; i++) L[i] *= inv;
}

#define PLDC 204
__global__ __launch_bounds__(256) void memscan(
    const float* __restrict__ proj, const float* __restrict__ memg_b,
    const float* __restrict__ mem_scale, float* __restrict__ gated)
{
  const int b = blockIdx.x / H, h = blockIdx.x % H;
  const int tid = threadIdx.x;
  __shared__ float S[256][22];
  const int base = tid * 8;
  const size_t rb = (size_t)b * T;

  float M[21];
#pragma unroll
  for (int c = 0; c < 21; c++) M[c] = 0.f;
  float sloc[8];

  for (int j = 0; j < 8; j++) {
    const int t = base + j;
    const float4 w2 = *(const float4*)(proj + (rb + t) * PLDC + 48 + h * 4);
    float C[21];
#pragma unroll
    for (int c = 0; c < 21; c++) C[c] = 0.f;
    const int offs[4] = {1, 2, 4, 8};
#pragma unroll
    for (int oi = 0; oi < 4; oi++) {
      const int off = offs[oi];
      if (t >= off) {
        const float4 w1 = *(const float4*)(proj + (rb + t - off) * PLDC + 0 + h * 4);
        float L[6];
        ext_norm6(w1, w2, L);
        const float Jv[6] = { L[5], -L[4], L[3], L[2], -L[1], L[0] };
        int c = 0;
#pragma unroll
        for (int p = 0; p < 6; p++)
#pragma unroll
          for (int q = p; q < 6; q++) { C[c] += Jv[p] * Jv[q]; c++; }
      }
    }
    float R[6];
    {
      const float4 r1 = *(const float4*)(proj + (rb + t) * PLDC + 96 + h * 4);
      const float4 r2 = *(const float4*)(proj + (rb + t) * PLDC + 144 + h * 4);
      ext_norm6(r1, r2, R);
    }
    float qd = 0.f;
    {
      int c = 0;
#pragma unroll
      for (int p = 0; p < 6; p++) {
        qd += M[c] * R[p] * R[p]; c++;
#pragma unroll
        for (int q = p + 1; q < 6; q++) { qd += 2.f * M[c] * R[p] * R[q]; c++; }
      }
    }
    sloc[j] = qd;
#pragma unroll
    for (int cc = 0; cc < 21; cc++) M[cc] = DECAY_F * (M[cc] + C[cc]);
  }

#pragma unroll
  for (int c = 0; c < 21; c++) S[tid][c] = M[c];
  __syncthreads();
  if (tid < 21) {
    float pv = 0.f;
    const float d8 = 0.92274469442792013f;  // 0.99^8
    for (int i = 0; i < 256; i++) {
      float a = S[i][tid];
      S[i][tid] = pv;
      pv = d8 * pv + a;
    }
  }
  __syncthreads();
  float P[21];
#pragma unroll
  for (int c = 0; c < 21; c++) P[c] = S[tid][c];

  const float msc = mem_scale[h];
  const float gb = memg_b[h];
  float dj = 1.f;
  for (int j = 0; j < 8; j++) {
    const int t = base + j;
    float R[6];
    {
      const float4 r1 = *(const float4*)(proj + (rb + t) * PLDC + 96 + h * 4);
      const float4 r2 = *(const float4*)(proj + (rb + t) * PLDC + 144 + h * 4);
      ext_norm6(r1, r2, R);
    }
    float qd = 0.f;
    {
      int c = 0;
#pragma unroll
      for (int p = 0; p < 6; p++) {
        qd += P[c] * R[p] * R[p]; c++;
#pragma unroll
        for (int q = p + 1; q < 6; q++) { qd += 2.f * P[c] * R[p] * R[q]; c++; }
      }
    }
    const float score = (sloc[j] + dj * qd) * 0.25f;
    const float g1 = 1.f / (1.f + __expf(-score * msc));
    const float graw = proj[(rb + t) * PLDC + 192 + h] + gb;
    const float g2 = 1.f / (1.f + __expf(-graw));
    atomicAdd(&gated[rb + t], g1 * g2 * (1.f / 12.f));
    dj *= DECAY_F;
  }
}

// ------- reduce partials + normalize + gate fuse -> bf16 z ---------------
__global__ __launch_bounds__(256) void reduce_fuse(
    const ushort* __restrict__ o_part, const float* __restrict__ rs_part,
    const ushort* __restrict__ memv, const float* __restrict__ gated,
    ushort* __restrict__ zb)
{
  const int idx = blockIdx.x * 256 + threadIdx.x;
  const int row = idx / 96, c = (idx % 96) * 8;
  const int h = c >> 6, d0 = c & 63;
  const int b = row >> 11, tl = row & (T - 1);
  const int qb = tl >> 7, rloc = tl & 127;
  const int m = qb >> 1;
  const int cnt = m + 1;
  const int base = m * (m + 1) + (qb & 1) * (m + 1);
  const size_t bid0 = (size_t)(b * H + h) * NCHK + base;

  float o[8] = {0.f, 0.f, 0.f, 0.f, 0.f, 0.f, 0.f, 0.f};
  float rsum = 0.f;
  for (int ci = 0; ci < cnt; ci++) {
    const bf16x8 pv = *(const bf16x8*)(o_part + ((bid0 + ci) * 128 + rloc) * 64 + d0);
#pragma unroll
    for (int j = 0; j < 8; j++) o[j] += bf2f((ushort)pv[j]);
    rsum += rs_part[(bid0 + ci) * 128 + rloc];
  }
  const float inv = 1.f / rsum;
  const float g = gated[row];
  const bf16x8 mv = *(const bf16x8*)(memv + (size_t)row * D + c);
  bf16x8 z;
#pragma unroll
  for (int j = 0; j < 8; j++)
    z[j] = (short)f2bf(o[j] * inv + g * bf2f((ushort)mv[j]));
  *(bf16x8*)(zb + (size_t)row * D + c) = z;
}

extern "C" void kernel_launch(void* const* d_in, const int* in_sizes, int n_in,
                              void* d_out, int out_size, void* d_ws, size_t ws_size,
                              hipStream_t stream)
{
  const float* x      = (const float*)d_in[0];
  const float* qkv_w  = (const float*)d_in[1];
  const float* qkv_b  = (const float*)d_in[2];
  const float* w1w    = (const float*)d_in[3];
  const float* w2w    = (const float*)d_in[4];
  const float* w1r    = (const float*)d_in[5];
  const float* w2r    = (const float*)d_in[6];
  const float* memv_w = (const float*)d_in[7];
  const float* memv_b = (const float*)d_in[8];
  const float* memg_w = (const float*)d_in[9];
  const float* memg_b = (const float*)d_in[10];
  const float* mem_scale = (const float*)d_in[11];
  const float* out_w  = (const float*)d_in[12];
  const float* out_b  = (const float*)d_in[13];
  float* out = (float*)d_out;

  float* ws    = (float*)d_ws;
  float* proj  = ws;                              // [4096][204] f32
  float* gated = proj + (size_t)NBT * PLDC;       // [4096]
  float* rs_part = gated + NBT;                   // [1728][128] f32
  ushort* memv = (ushort*)(rs_part + (size_t)NBLK_ATTN * 128); // [4096][768] bf16
  ushort* Xb  = memv + (size_t)NBT * D;           // [4096][768] bf16
  ushort* Wb  = Xb + (size_t)NBT * D;             // cast_all weight rows
  ushort* Qb  = Wb + (size_t)NBT * D;             // [24][2048][64]
  ushort* Kb  = Qb + (size_t)24 * T * 64;
  ushort* Vtb = Kb + (size_t)24 * T * 64;         // [24][64][2048]
  ushort* zb  = Vtb + (size_t)24 * T * 64;        // [4096][768]
  ushort* o_part = zb + (size_t)NBT * D;          // [1728][128][64] bf16

  const ushort* W_out = Wb + (size_t)3328 * 768;

  dim3 blk(256);
  cast_all<<<dim3(3072), blk, 0, stream>>>(x, qkv_w, memv_w, out_w,
                                           w1w, w2w, w1r, w2r, memg_w, Xb);

  // merged qkv + memv + proj GEMM, 8-phase 256x256 (N = 3328 incl. zero-pad)
  gemm8_mega<<<dim3(16 * 13), dim3(512), 0, stream>>>(
      Xb, Wb, qkv_b, memv_b, memv, proj, Qb, Kb, Vtb);

  hipMemsetAsync(gated, 0, NBT * sizeof(float), stream);

  attn_mfma<<<dim3(NBLK_ATTN), blk, 0, stream>>>(Qb, Kb, Vtb, o_part, rs_part);
  memscan<<<dim3(2 * H), blk, 0, stream>>>(proj, memg_b, mem_scale, gated);

  reduce_fuse<<<dim3(NBT * 96 / 256), blk, 0, stream>>>(o_part, rs_part, memv,
                                                        gated, zb);
  gemm_mfma128<<<dim3(6, 32), blk, 0, stream>>>(zb, W_out, out_b, out, 768);
}